// Round 6
// baseline (440.584 us; speedup 1.0000x reference)
//
#include <hip/hip_runtime.h>
#include <hip/hip_bf16.h>
#include <math.h>

// ---------------------------------------------------------------------------
// HydraFusionHead: B=4, IN_CH=256, HEAD_CH=64, H=W=128, NH=4, KEY=VAL=16
// Round-17: conv_base gets the kv round-16 treatment. Diagnosis (same
// arithmetic that fixed kv): each conv_base block re-reads the full 864 KB wA
// panel from L2 -> 15.4K cy L2 vs 4.2K cy MFMA -> util cap 27% (measured 24%).
// Fix: full-row N=128 blocks (grid 128x4): A-fragment register reuse doubles
// (8 MFMAs/A-load), chip A-traffic 905->442 MB, util cap -> 54%.
// Staging: per-s-group 24.96 KB tile, double-buffered (49.9 KB), 8 phases.
// kv_all4 (round-16), conv_head, attn, setup unchanged.
// ---------------------------------------------------------------------------

#define HW 16384
#define WIMG 128

typedef unsigned short ushortT;
typedef __attribute__((ext_vector_type(8))) short short8;
typedef __attribute__((ext_vector_type(4))) float floatx4;
typedef __attribute__((ext_vector_type(4))) unsigned uintx4;

// ws layout (float offsets)
constexpr size_t OFF_KV    = 16777216;             // bf16 [3][4][128][HW] channel-major
constexpr size_t OFF_A16   = 29360128;             // bf16 [4][32][130][130][8]
constexpr size_t OFF_B16   = 38012928;             // bf16 [4][28][134][134][8]
constexpr size_t OFF_CWT   = 46057216;             // bf16 wA [9][32][192][8]
constexpr size_t OFF_CB    = OFF_CWT + 221184;     // [3][64] fp32
constexpr size_t OFF_HWT   = OFF_CB + 192;         // bf16 wH [3][72][16][8]
constexpr size_t OFF_QWT   = OFF_HWT + 13824;      // bf16 wQ
constexpr size_t OFF_QB    = OFF_QWT + 8192;       // [64]
constexpr size_t OFF_KVW   = OFF_QB + 64;          // bf16 W_eff group-major [532480]
constexpr size_t OFF_GEO   = OFF_KVW + 266240;     // fp32 [3][3][128]
constexpr size_t OFF_P1WT  = OFF_GEO + 1152;       // bf16 wP1
constexpr size_t OFF_P1B   = OFF_P1WT + 40960;     // [256]

struct P53 { const float* p[53]; };

__device__ inline ushortT f2bf(float f) {
    unsigned u = __float_as_uint(f);
    unsigned r = (u + 0x7FFFu + ((u >> 16) & 1u)) >> 16;
    return (ushortT)r;
}
__device__ inline unsigned packbf(float a, float b) {
    return (unsigned)f2bf(a) | ((unsigned)f2bf(b) << 16);
}
__device__ inline float bf2f(ushortT u) {
    return __uint_as_float((unsigned)u << 16);
}

// async global->LDS 16B: lds dst = wave-uniform base + lane*16
typedef __attribute__((address_space(3))) ushortT lds_us;
typedef __attribute__((address_space(1))) const ushortT glb_us;
__device__ inline void gload_lds16(const ushortT* g, ushortT* ldsbase) {
    __builtin_amdgcn_global_load_lds((glb_us*)g, (lds_us*)ldsbase, 16, 0, 0);
}

// sample-point offsets (pixel units), faithful to torch .view(2,n) reinterpret
__device__ const float c_ox[3][9] = {
    {-1.f, 0.f, 1.f, -1.f, 0.f, 1.f, -1.f, 0.f, 1.f},
    {-1.f, 2.4375f, -1.f, -2.4375f, 1.f, 2.4375f, 1.f, -2.4375f, 0.f},
    {-1.625f, -1.625f, -1.625f, 0.f, -1.625f, 1.625f, 0.f, -1.625f, 0.f}};
__device__ const float c_oy[3][9] = {
    {-1.f, -1.f, -1.f, 0.f, 0.f, 0.f, 1.f, 1.f, 1.f},
    {2.4375f, -1.f, -2.4375f, -1.f, 2.4375f, 1.f, -2.4375f, 1.f, 0.f},
    {0.f, 0.f, 1.625f, 1.625f, -1.625f, 1.625f, 0.f, 1.625f, 1.625f}};

// corner-branch tap tables (16 taps)
__device__ const int tapX_cor[16] = {-1,-1, 2, 3,-1,-1,-3,-2, 1, 1, 2, 3, 1, 1,-3,-2};
__device__ const int tapY_cor[16] = { 2, 3,-1,-1,-3,-2,-1,-1, 2, 3, 1, 1,-3,-2, 1, 1};
__device__ const int tapR_cor[16] = { 4, 5, 2, 2, 0, 1, 2, 2, 4, 5, 3, 3, 0, 1, 3, 3};

__device__ inline float cornw(float off, int X) {
    float f = floorf(off);
    float d = off - f;
    int fi = (int)f;
    return (X == fi) ? (1.f - d) : (X == fi + 1) ? d : 0.f;
}

// ------------- setup: fold BN + transpose weights + pass_a/b borders --------
__global__ __launch_bounds__(256) void setup_kernel(P53 ptrs, float* __restrict__ ws,
                                                    const float* __restrict__ base,
                                                    ushortT* __restrict__ a16,
                                                    ushortT* __restrict__ b16) {
    int i = blockIdx.x * 256 + threadIdx.x;
    const float* const* p = ptrs.p;
    if (i < 1102464) {
        if (i < 442368) {  // bf16 wA[tap][g32][M192][j8], ic = g*8+j
            int tap = i / 49152, r = i % 49152;
            int g = r / 1536, r2 = r % 1536;
            int M = r2 >> 3, j = r2 & 7;
            int br = M >> 6, oc = M & 63, ic = g * 8 + j;
            float v = p[1 + 6 * br][(oc * 256 + ic) * 9 + tap] * p[3 + 6 * br][oc];
            ((ushortT*)(ws + OFF_CWT))[i] = f2bf(v);
            return;
        }
        i -= 442368;
        if (i < 192) {
            int br = i >> 6, oc = i & 63;
            ws[OFF_CB + i] = p[2 + 6 * br][oc] * p[3 + 6 * br][oc] + p[4 + 6 * br][oc];
            return;
        }
        i -= 192;
        if (i < 27648) {  // bf16 wH[br][u72][m16][j8]
            int j = i & 7, m = (i >> 3) & 15, u = (i >> 7) % 72, br = i / 9216;
            int cnt = (br == 1) ? 12 : 3;
            int t = u >> 3, g = u & 7, ic = g * 8 + j;
            const float* hw = (br == 0) ? p[5] : (br == 1) ? p[11] : p[17];
            float v = (m < cnt) ? hw[(m * 64 + ic) * 9 + t] : 0.f;
            ((ushortT*)(ws + OFF_HWT))[i] = f2bf(v);
            return;
        }
        i -= 27648;
        if (i < 16384) {  // bf16 wQ[kk8][sub4][m64][j8]
            int j = i & 7, m = (i >> 3) & 63, sg = i >> 9;
            int k = (sg >> 2) * 32 + (sg & 3) * 8 + j;
            ((ushortT*)(ws + OFF_QWT))[i] = f2bf(p[19][m * 256 + k] * p[21][m]);
            return;
        }
        i -= 16384;
        if (i < 64) { ws[OFF_QB + i] = p[20][i] * p[21][i] + p[22][i]; return; }
        i -= 64;
        if (i < 532480) {  // W_eff bf16 group-major: [br][g][q][sub][m128][j8]
            int br, NQ, NTAP, n, C, i2;
            if (i < 110592)      { br = 0; NQ = 3; NTAP = 9;  n = 9; C = 67; i2 = i; }
            else if (i < 274432) { br = 1; NQ = 4; NTAP = 16; n = 8; C = 76; i2 = i - 110592; }
            else                 { br = 2; NQ = 7; NTAP = 25; n = 9; C = 67; i2 = i - 274432; }
            int gsz = NQ * 4096;
            int g = i2 / gsz, r = i2 % gsz;
            int q = r >> 12, r2 = r & 4095;
            int sub = r2 >> 10, m = (r2 >> 3) & 127, j = r2 & 7;
            int t = q * 4 + sub, c = g * 8 + j;
            float v = 0.f;
            if (t < NTAP && c < C) {
                int X, Y;
                if (br == 0)      { X = t % 3 - 1; Y = t / 3 - 1; }
                else if (br == 1) { X = tapX_cor[t]; Y = tapY_cor[t]; }
                else              { X = t % 5 - 2; Y = t / 5 - 2; }
                const float* wsrc = (m < 64) ? p[23 + 8 * br] : p[27 + 8 * br];
                int mo = (m < 64) ? m : m - 64;
                float sc = (m < 64) ? p[25 + 8 * br][mo] : p[29 + 8 * br][mo];
                int Cn = (C + 2) * n;
                float s = 0.f;
                for (int pp = 0; pp < n; ++pp) {
                    float ww = cornw(c_ox[br][pp], X) * cornw(c_oy[br][pp], Y);
                    if (ww != 0.f) s += ww * wsrc[mo * Cn + c * n + pp];
                }
                v = s * sc;
            }
            ((ushortT*)(ws + OFF_KVW))[i] = f2bf(v);
            return;
        }
        i -= 532480;
        if (i < 1152) {  // geo GA/GB/GC [br][which][128]
            int br = i / 384, rem = i % 384, which = rem >> 7, m = rem & 127;
            int n = (br == 1) ? 8 : 9, C = (br == 1) ? 76 : 67, Cn = (C + 2) * n;
            const float* wsrc = (m < 64) ? p[23 + 8 * br] : p[27 + 8 * br];
            int mo = (m < 64) ? m : m - 64;
            float sc = (m < 64) ? p[25 + 8 * br][mo] : p[29 + 8 * br][mo];
            float bb = (m < 64) ? p[24 + 8 * br][mo] : p[28 + 8 * br][mo];
            float tt = (m < 64) ? p[26 + 8 * br][mo] : p[30 + 8 * br][mo];
            float v = 0.f;
            if (which == 0) {
                for (int pp = 0; pp < n; ++pp) v += wsrc[mo * Cn + C * n + pp];
                v *= sc;
            } else if (which == 1) {
                for (int pp = 0; pp < n; ++pp) v += wsrc[mo * Cn + (C + 1) * n + pp];
                v *= sc;
            } else {
                for (int pp = 0; pp < n; ++pp)
                    v += wsrc[mo * Cn + C * n + pp] * c_ox[br][pp]
                       + wsrc[mo * Cn + (C + 1) * n + pp] * c_oy[br][pp];
                v = v * sc * 0.0078125f + bb * sc + tt;
            }
            ws[OFF_GEO + br * 384 + which * 128 + m] = v;
            return;
        }
        i -= 1152;
        if (i < 81920) {  // bf16 wP1[kk10][sub4][M256][j8], K=320 extended
            int j = i & 7, M = (i >> 3) & 255, sg = i >> 11;
            int k = (sg >> 2) * 32 + (sg & 3) * 8 + j;
            int nh = M >> 6, oc = M & 63;
            float sc = p[49][nh * 64 + oc];
            float v;
            if (k < 256) v = p[47][(nh * 64 + oc) * 272 + k] * sc;
            else {
                int k2 = k - 256, nh2 = k2 >> 4, va = k2 & 15;
                v = (nh2 == nh) ? p[47][(nh * 64 + oc) * 272 + 256 + va] * sc : 0.f;
            }
            ((ushortT*)(ws + OFF_P1WT))[i] = f2bf(v);
            return;
        }
        i -= 81920;
        if (i < 256) { ws[OFF_P1B + i] = p[48][i] * p[49][i] + p[50][i]; }
        return;
    }
    int idx = i - 1102464;
    if (idx < 4 * 32 * 130 * 130) {  // pass A: base -> a16 (pad 1)
        int col = idx % 130, t = idx / 130;
        int row = t % 130; t /= 130;
        int icg = t & 31, b = t >> 5;
        int h = row - 1, w = col - 1;
        unsigned wds[4] = {0u, 0u, 0u, 0u};
        if ((unsigned)h < 128u && (unsigned)w < 128u) {
            const float* s = base + (size_t)(b * 256 + icg * 8) * HW + h * WIMG + w;
            #pragma unroll
            for (int jp = 0; jp < 4; ++jp)
                wds[jp] = packbf(s[(size_t)(2 * jp) * HW], s[(size_t)(2 * jp + 1) * HW]);
        }
        unsigned* d = (unsigned*)(a16 + (size_t)idx * 8);
        d[0] = wds[0]; d[1] = wds[1]; d[2] = wds[2]; d[3] = wds[3];
        return;
    }
    idx -= 4 * 32 * 130 * 130;
    if (idx < 4 * 28 * 134 * 134) {  // b16 3-px apron zero
        int col = idx % 134, row = (idx / 134) % 134;
        if (row < 3 || row >= 131 || col < 3 || col >= 131) {
            unsigned* d = (unsigned*)(b16 + (size_t)idx * 8);
            d[0] = 0u; d[1] = 0u; d[2] = 0u; d[3] = 0u;
        }
    }
}

// ---- conv3x3 base(256) -> 192 feats via 16x16x32 bf16 MFMA -> b16 ----------
// Full-row blocks (N=128): A-fragment register reuse x8 (was x4); grid (128,4).
__global__ __launch_bounds__(256) void conv_base_mfma(
    const ushortT* __restrict__ a16, const ushortT* __restrict__ wA,
    const float* __restrict__ cb, ushortT* __restrict__ b16)
{
    const int wv = threadIdx.x >> 6, lane = threadIdx.x & 63;
    const int sub = lane >> 4, ln = lane & 15;
    const int h = blockIdx.x, b = blockIdx.y;
    __shared__ __align__(16) ushortT sbuf[2][1560 * 8];  // 49,920 B

    floatx4 acc[3][8];
    #pragma unroll
    for (int mt = 0; mt < 3; ++mt)
        #pragma unroll
        for (int nt = 0; nt < 8; ++nt)
            #pragma unroll
            for (int r = 0; r < 4; ++r) acc[mt][nt][r] = 0.f;

    const int wbase = threadIdx.x & ~63;
    auto stage = [&](int s, int buf) {
        #pragma unroll
        for (int it = 0; it < 7; ++it) {
            int idx = threadIdx.x + it * 256;
            if (idx < 1560) {
                int col = idx % 130, t2 = idx / 130;
                int r = t2 % 3, icg = t2 / 3;
                const ushortT* g = a16 +
                    (((size_t)(b * 32 + s * 4 + icg) * 130 + (h + r)) * 130 + col) * 8;
                gload_lds16(g, &sbuf[buf][(size_t)(it * 256 + wbase) * 8]);
            }
        }
    };
    stage(0, 0);
    for (int s = 0; s < 8; ++s) {
        __syncthreads();
        if (s < 7) stage(s + 1, (s + 1) & 1);
        const ushortT* sb = sbuf[s & 1];
        #pragma unroll
        for (int tap = 0; tap < 9; ++tap) {
            const int ky = tap / 3, kx = tap % 3;
            const int g = s * 4 + sub;
            short8 Af[3];
            #pragma unroll
            for (int mt = 0; mt < 3; ++mt) {
                int m = wv * 48 + mt * 16 + ln;
                Af[mt] = *(const short8*)(wA + (((size_t)tap * 32 + g) * 192 + m) * 8);
            }
            #pragma unroll
            for (int nt = 0; nt < 8; ++nt) {
                int c = nt * 16 + ln + kx;
                short8 Bf = *(const short8*)(sb + ((sub * 3 + ky) * 130 + c) * 8);
                #pragma unroll
                for (int mt = 0; mt < 3; ++mt)
                    acc[mt][nt] = __builtin_amdgcn_mfma_f32_16x16x32_bf16(
                        Af[mt], Bf, acc[mt][nt], 0, 0, 0);
            }
        }
    }
    #pragma unroll
    for (int mt = 0; mt < 3; ++mt) {
        int ocq = wv * 48 + mt * 16 + sub * 4;
        #pragma unroll
        for (int nt = 0; nt < 8; ++nt) {
            int px = nt * 16 + ln;
            float v0 = fmaxf(acc[mt][nt][0] + cb[ocq + 0], 0.f);
            float v1 = fmaxf(acc[mt][nt][1] + cb[ocq + 1], 0.f);
            float v2 = fmaxf(acc[mt][nt][2] + cb[ocq + 2], 0.f);
            float v3 = fmaxf(acc[mt][nt][3] + cb[ocq + 3], 0.f);
            unsigned lo = packbf(v0, v1), hi = packbf(v2, v3);
            unsigned plo = (unsigned)__shfl_down((int)lo, 16);
            unsigned phi = (unsigned)__shfl_down((int)hi, 16);
            if (!(sub & 1)) {
                int br = ocq >> 6, oc = ocq & 63;
                int grp = ((br == 0) ? 0 : (br == 1) ? 9 : 19) + (oc >> 3);
                uintx4 w = {lo, hi, plo, phi};
                *(uintx4*)(b16 +
                    (((size_t)(b * 28 + grp) * 134 + (h + 3)) * 134 + (px + 3)) * 8) = w;
            }
        }
    }
}

// ---- head 3x3 convs via MFMA, half-row tiles (M=16 padded maps, K=576) -----
__global__ __launch_bounds__(256) void conv_head_mfma(
    const ushortT* __restrict__ b16c, const ushortT* __restrict__ wH,
    const float* __restrict__ chb, const float* __restrict__ ohb,
    const float* __restrict__ fhb, float* __restrict__ out,
    ushortT* __restrict__ b16)
{
    const int wv = threadIdx.x >> 6, lane = threadIdx.x & 63;
    const int sub = lane >> 4, ln = lane & 15;
    const int x0 = (blockIdx.x & 1) * 64, h = blockIdx.x >> 1;
    const int br = blockIdx.y % 3, b = blockIdx.y / 3;
    const int cnt = (br == 1) ? 12 : 3;
    const int mapb = (br == 0) ? 0 : (br == 1) ? 3 : 15;
    const int grpb = (br == 0) ? 0 : (br == 1) ? 9 : 19;
    const float* bias = (br == 0) ? chb : (br == 1) ? ohb : fhb;
    __shared__ __align__(16) ushortT sbuf[8 * 3 * 66 * 8];  // 25,344 B
    const int wbase = threadIdx.x & ~63;

    for (int it = 0; it < 7; ++it) {
        int idx = threadIdx.x + it * 256;
        if (idx < 1584) {
            int col = idx % 66, t2 = idx / 66;
            int r = t2 % 3, g = t2 / 3;
            const ushortT* gp = b16c +
                (((size_t)(b * 28 + grpb + g) * 134 + (h + r + 2)) * 134 + (x0 + col + 2)) * 8;
            gload_lds16(gp, sbuf + (size_t)(it * 256 + wbase) * 8);
        }
    }
    __syncthreads();

    floatx4 acc;
    #pragma unroll
    for (int r = 0; r < 4; ++r) acc[r] = 0.f;
    #pragma unroll
    for (int k = 0; k < 18; ++k) {
        int u = k * 4 + sub;
        int t = u >> 3, g = u & 7;
        int dxv = t % 3 - 1, ry = t / 3;
        short8 Af = *(const short8*)(wH + ((size_t)(br * 72 + u) * 16 + ln) * 8);
        int c = wv * 16 + ln + dxv + 1;
        short8 Bf = *(const short8*)(sbuf + ((g * 3 + ry) * 66 + c) * 8);
        acc = __builtin_amdgcn_mfma_f32_16x16x32_bf16(Af, Bf, acc, 0, 0, 0);
    }
    {
        int px = x0 + wv * 16 + ln;
        #pragma unroll
        for (int r = 0; r < 4; ++r) {
            int m = sub * 4 + r;
            if (m < cnt) {
                float v = acc[r] + bias[m];
                out[((size_t)b * 26 + mapb + m) * HW + h * WIMG + px] = v;
                int grp = grpb + 8 + (m >> 3), j = m & 7;
                b16[(((size_t)(b * 28 + grp) * 134 + (h + 3)) * 134 + (px + 3)) * 8 + j]
                    = f2bf(v);
            }
        }
    }
}

// ------ kv: sparse-tap conv, full-row N=128 blocks, per-group staging -------
template<int BRV>
__device__ __forceinline__ void kv_body(
    const ushortT* __restrict__ b16, const ushortT* __restrict__ kvw,
    const float* __restrict__ geob, ushortT* __restrict__ kvout,
    ushortT* __restrict__ sbuf, int h, int b)
{
    constexpr int NG   = (BRV == 0) ? 9 : (BRV == 1) ? 10 : 9;   // channel groups
    constexpr int NTAP = (BRV == 0) ? 9 : (BRV == 1) ? 16 : 25;
    constexpr int NQ   = (BRV == 0) ? 3 : (BRV == 1) ? 4 : 7;    // tap quads (padded)
    constexpr int ROWS = (BRV == 0) ? 3 : (BRV == 1) ? 6 : 5;
    constexpr int COLS = (BRV == 0) ? 130 : (BRV == 1) ? 134 : 132;  // 128 + x-apron
    constexpr int XMIN = (BRV == 0) ? -1 : (BRV == 1) ? -3 : -2;
    constexpr int UBASE = (BRV == 0) ? 0 : (BRV == 1) ? 9 : 19;
    constexpr int NEL  = ROWS * COLS;            // 390 / 804 / 660 per group
    constexpr int NIT  = (NEL + 255) / 256;
    constexpr int WBASE = (BRV == 0) ? 0 : (BRV == 1) ? 110592 : 274432;  // ushorts

    const int lane = threadIdx.x & 63, wv = threadIdx.x >> 6;
    const int sub = lane >> 4, ln = lane & 15;
    const int wbase = threadIdx.x & ~63;
    const int thrB = ln * 16;

    // per-quad B byte offsets within the full-row group tile
    int boff[NQ];
    #pragma unroll
    for (int q = 0; q < NQ; ++q) {
        int t = q * 4 + sub;
        int dxv, ry;
        if (t >= NTAP)          { dxv = -XMIN; ry = 0; }  // padded tap: zero wt, safe addr
        else if (BRV == 0)      { dxv = t % 3 - 1; ry = t / 3; }
        else if (BRV == 1)      { dxv = tapX_cor[t]; ry = tapR_cor[t]; }
        else                    { dxv = t % 5 - 2; ry = t / 5; }
        boff[q] = (ry * COLS + (dxv - XMIN)) * 16 + thrB;
    }

    auto stage = [&](int g) {
        #pragma unroll
        for (int it = 0; it < NIT; ++it) {
            int idx = threadIdx.x + it * 256;
            if (idx < NEL) {
                int rw = idx / COLS, col = idx % COLS;
                int dy = (BRV == 1) ? ((rw < 3) ? rw - 3 : rw - 2) : (rw - ROWS / 2);
                const ushortT* gp = b16 +
                    (((size_t)(b * 28 + UBASE + g) * 134 + (h + dy + 3)) * 134
                     + (col + XMIN + 3)) * 8;
                gload_lds16(gp, sbuf + (size_t)(it * 256 + wbase) * 8);
            }
        }
    };

    floatx4 acc[2][8];
    #pragma unroll
    for (int mt = 0; mt < 2; ++mt)
        #pragma unroll
        for (int nt = 0; nt < 8; ++nt)
            #pragma unroll
            for (int r = 0; r < 4; ++r) acc[mt][nt][r] = 0.f;

    const ushortT* wp0 = kvw + WBASE + (size_t)sub * 1024 + (wv * 32 + ln) * 8;

    for (int g = 0; g < NG; ++g) {
        if (g) __syncthreads();             // WAR: all waves done reading buffer
        stage(g);
        __syncthreads();                    // drains stage (vmcnt 0): LDS visible
        const char* sb8 = (const char*)sbuf;
        const ushortT* wg = wp0 + (size_t)g * (NQ * 4096);
        #pragma unroll
        for (int q = 0; q < NQ; ++q) {
            short8 A0 = *(const short8*)(wg + (size_t)q * 4096);
            short8 A1 = *(const short8*)(wg + (size_t)q * 4096 + 128);
            int bb = boff[q];
            #pragma unroll
            for (int nt = 0; nt < 8; ++nt) {
                short8 Bf = *(const short8*)(sb8 + bb + nt * 256);
                acc[0][nt] = __builtin_amdgcn_mfma_f32_16x16x32_bf16(A0, Bf, acc[0][nt], 0, 0, 0);
                acc[1][nt] = __builtin_amdgcn_mfma_f32_16x16x32_bf16(A1, Bf, acc[1][nt], 0, 0, 0);
            }
        }
    }

    // epilogue: + GA*fx + GB*fy + GC, relu, channel-major bf16 (full 256B lines)
    const float* geo = geob + BRV * 384;
    const float fy = (h + 0.5f) * 0.0078125f;
    #pragma unroll
    for (int mt = 0; mt < 2; ++mt)
        #pragma unroll
        for (int nt = 0; nt < 8; ++nt) {
            int px = nt * 16 + ln;
            float fx = (px + 0.5f) * 0.0078125f;
            #pragma unroll
            for (int r = 0; r < 4; ++r) {
                int Mi = wv * 32 + mt * 16 + sub * 4 + r;
                float v = acc[mt][nt][r] + geo[Mi] * fx + geo[128 + Mi] * fy + geo[256 + Mi];
                kvout[((size_t)(BRV * 4 + b) * 128 + Mi) * HW + h * WIMG + px] =
                    f2bf(fmaxf(v, 0.f));
            }
        }
}

__global__ __launch_bounds__(256, 4) void kv_all4(
    const ushortT* __restrict__ b16, const ushortT* __restrict__ kvw,
    const float* __restrict__ geob, ushortT* __restrict__ kvout)
{
    __shared__ __align__(16) ushortT sbuf[804 * 8];  // union max (br1): 12,864 B
    const int h = blockIdx.x;
    const int z = blockIdx.y;            // brv*4 + b
    const int brv = z >> 2, b = z & 3;
    if (brv == 0)      kv_body<0>(b16, kvw, geob, kvout, sbuf, h, b);
    else if (brv == 1) kv_body<1>(b16, kvw, geob, kvout, sbuf, h, b);
    else               kv_body<2>(b16, kvw, geob, kvout, sbuf, h, b);
}

// -------- fused q-GEMM + attention softmax + p1(MFMA,K=320) + p2 ------------
__global__ __launch_bounds__(256) void attn_pred_mfma(
    float* __restrict__ ws, const float* __restrict__ p2w,
    const float* __restrict__ p2b, float* __restrict__ out)
{
    const int wv = threadIdx.x >> 6, lane = threadIdx.x & 63;
    const int sub = lane >> 4, ln = lane & 15;
    const int px0 = blockIdx.x * 64, b = blockIdx.y;
    const ushortT* wP1 = (const ushortT*)(ws + OFF_P1WT);
    const ushortT* wQ  = (const ushortT*)(ws + OFF_QWT);
    const ushortT* a16 = (const ushortT*)(ws + OFF_A16);
    const ushortT* kv = (const ushortT*)(ws + OFF_KV);
    const float* p1b = ws + OFF_P1B;
    const float* qb  = ws + OFF_QB;
    __shared__ __align__(16) ushortT xbuf[40 * 64 * 8];
    __shared__ __align__(16) ushortT qld[64 * 64];

    const int mypx = threadIdx.x & 63, nh = threadIdx.x >> 6;
    const int gpx = px0 + mypx, hh = gpx >> 7, ww = gpx & 127;
    #pragma unroll
    for (int g2 = 0; g2 < 8; ++g2) {
        int g = nh * 8 + g2;
        const ushortT* gp = a16 +
            (((size_t)(b * 32 + g) * 130 + (hh + 1)) * 130 + (ww + 1)) * 8;
        gload_lds16(gp, xbuf + (size_t)g * 64 * 8);
    }
    __syncthreads();

    {
        floatx4 qacc[4];
        #pragma unroll
        for (int nt = 0; nt < 4; ++nt)
            #pragma unroll
            for (int r = 0; r < 4; ++r) qacc[nt][r] = 0.f;
        #pragma unroll
        for (int kk = 0; kk < 8; ++kk) {
            short8 Af = *(const short8*)(wQ + (((kk * 4 + sub) * 64) + wv * 16 + ln) * 8);
            #pragma unroll
            for (int nt = 0; nt < 4; ++nt) {
                short8 Bf = *(const short8*)(xbuf + (((kk * 4 + sub) * 64) + nt * 16 + ln) * 8);
                qacc[nt] = __builtin_amdgcn_mfma_f32_16x16x32_bf16(Af, Bf, qacc[nt], 0, 0, 0);
            }
        }
        #pragma unroll
        for (int nt = 0; nt < 4; ++nt)
            #pragma unroll
            for (int r = 0; r < 4; ++r) {
                int row = wv * 16 + sub * 4 + r;
                qld[row * 64 + nt * 16 + ln] = f2bf(fmaxf(qacc[nt][r] + qb[row], 0.f));
            }
    }
    __syncthreads();

    {
        float l[3];
        #pragma unroll
        for (int br = 0; br < 3; ++br) {
            float s = 0.f;
            #pragma unroll
            for (int ko = 0; ko < 16; ++ko)
                s = fmaf(bf2f(qld[(nh * 16 + ko) * 64 + mypx]),
                         bf2f(kv[(size_t)((br * 4 + b) * 128 + nh * 16 + ko) * HW + gpx]), s);
            l[br] = s;
        }
        float m = fmaxf(l[0], fmaxf(l[1], l[2]));
        float e0 = __expf(l[0] - m), e1 = __expf(l[1] - m), e2 = __expf(l[2] - m);
        float inv = 1.f / (e0 + e1 + e2);
        float aw0 = e0 * inv, aw1 = e1 * inv, aw2 = e2 * inv;
        #pragma unroll
        for (int vap = 0; vap < 8; ++vap) {
            int va0 = vap * 2, va1 = vap * 2 + 1;
            float a0 =
                aw0 * bf2f(kv[(size_t)((0 * 4 + b) * 128 + 64 + nh * 16 + va0) * HW + gpx]) +
                aw1 * bf2f(kv[(size_t)((1 * 4 + b) * 128 + 64 + nh * 16 + va0) * HW + gpx]) +
                aw2 * bf2f(kv[(size_t)((2 * 4 + b) * 128 + 64 + nh * 16 + va0) * HW + gpx]);
            float a1 =
                aw0 * bf2f(kv[(size_t)((0 * 4 + b) * 128 + 64 + nh * 16 + va1) * HW + gpx]) +
                aw1 * bf2f(kv[(size_t)((1 * 4 + b) * 128 + 64 + nh * 16 + va1) * HW + gpx]) +
                aw2 * bf2f(kv[(size_t)((2 * 4 + b) * 128 + 64 + nh * 16 + va1) * HW + gpx]);
            int g = 32 + nh * 2 + (vap >> 2), wo = vap & 3;
            ((unsigned*)xbuf)[(g * 64 + mypx) * 4 + wo] = packbf(a0, a1);
        }
    }
    __syncthreads();

    floatx4 acc[4][4];
    #pragma unroll
    for (int mt = 0; mt < 4; ++mt)
        #pragma unroll
        for (int nt = 0; nt < 4; ++nt)
            #pragma unroll
            for (int r = 0; r < 4; ++r) acc[mt][nt][r] = 0.f;
    #pragma unroll
    for (int kk = 0; kk < 10; ++kk) {
        short8 Bf[4];
        #pragma unroll
        for (int nt = 0; nt < 4; ++nt)
            Bf[nt] = *(const short8*)(xbuf + (((kk * 4 + sub) * 64) + nt * 16 + ln) * 8);
        #pragma unroll
        for (int mt = 0; mt < 4; ++mt) {
            short8 Af = *(const short8*)(wP1 +
                (((size_t)(kk * 4 + sub) * 256) + wv * 64 + mt * 16 + ln) * 8);
            #pragma unroll
            for (int nt = 0; nt < 4; ++nt)
                acc[mt][nt] = __builtin_amdgcn_mfma_f32_16x16x32_bf16(Af, Bf[nt], acc[mt][nt], 0, 0, 0);
        }
    }

    float po0[4] = {0.f, 0.f, 0.f, 0.f}, po1[4] = {0.f, 0.f, 0.f, 0.f};
    #pragma unroll
    for (int mt = 0; mt < 4; ++mt)
        #pragma unroll
        for (int r = 0; r < 4; ++r) {
            int oc = mt * 16 + sub * 4 + r;
            float bias = p1b[wv * 64 + oc];
            float w0 = p2w[(wv * 2 + 0) * 64 + oc];
            float w1 = p2w[(wv * 2 + 1) * 64 + oc];
            #pragma unroll
            for (int nt = 0; nt < 4; ++nt) {
                float hv = fmaxf(acc[mt][nt][r] + bias, 0.f);
                po0[nt] = fmaf(w0, hv, po0[nt]);
                po1[nt] = fmaf(w1, hv, po1[nt]);
            }
        }
    #pragma unroll
    for (int nt = 0; nt < 4; ++nt) {
        po0[nt] += __shfl_xor(po0[nt], 16);
        po0[nt] += __shfl_xor(po0[nt], 32);
        po1[nt] += __shfl_xor(po1[nt], 16);
        po1[nt] += __shfl_xor(po1[nt], 32);
    }
    if (sub == 0) {
        #pragma unroll
        for (int nt = 0; nt < 4; ++nt) {
            int px = px0 + nt * 16 + ln;
            out[((size_t)b * 26 + 18 + wv * 2 + 0) * HW + px] = po0[nt] + p2b[wv * 2 + 0];
            out[((size_t)b * 26 + 18 + wv * 2 + 1) * HW + px] = po1[nt] + p2b[wv * 2 + 1];
        }
    }
}

// ---------------------------------------------------------------------------
extern "C" void kernel_launch(void* const* d_in, const int* in_sizes, int n_in,
                              void* d_out, int out_size, void* d_ws, size_t ws_size,
                              hipStream_t stream) {
    (void)in_sizes; (void)n_in; (void)out_size; (void)ws_size;
    float* ws  = (float*)d_ws;
    float* out = (float*)d_out;
    const float* base = (const float*)d_in[0];
    P53 ptrs;
    for (int i = 0; i < 53; ++i) ptrs.p[i] = (const float*)d_in[i];

    ushortT* a16 = (ushortT*)(ws + OFF_A16);
    ushortT* b16 = (ushortT*)(ws + OFF_B16);
    ushortT* kvb = (ushortT*)(ws + OFF_KV);
    const ushortT* kvw = (const ushortT*)(ws + OFF_KVW);

    setup_kernel<<<20613, 256, 0, stream>>>(ptrs, ws, base, a16, b16);
    conv_base_mfma<<<dim3(128, 4), 256, 0, stream>>>(
        a16, (const ushortT*)(ws + OFF_CWT), ws + OFF_CB, b16);
    conv_head_mfma<<<dim3(256, 12), 256, 0, stream>>>(
        b16, (const ushortT*)(ws + OFF_HWT),
        (const float*)d_in[6], (const float*)d_in[12], (const float*)d_in[18],
        out, b16);
    kv_all4<<<dim3(128, 12), 256, 0, stream>>>(b16, kvw, ws + OFF_GEO, kvb);
    attn_pred_mfma<<<dim3(256, 4), 256, 0, stream>>>(ws, (const float*)d_in[51],
                                                     (const float*)d_in[52], out);
}

// Round 7
// 411.535 us; speedup vs baseline: 1.0706x; 1.0706x over previous
//
#include <hip/hip_runtime.h>
#include <hip/hip_bf16.h>
#include <math.h>

// ---------------------------------------------------------------------------
// HydraFusionHead: B=4, IN_CH=256, HEAD_CH=64, H=W=128, NH=4, KEY=VAL=16
// Round-18 theory: both MFMA conv kernels are stall-bound on in-order vmcnt
// force-drain: a gload_lds stage issued BEFORE the phase's global A-loads is
// force-retired at the first A-consume (full stage latency on the critical
// path every phase). r3 tested the fix but confounded it with an XCD swizzle
// that doubled WRITE traffic (r4 proved swizzle was the poison). De-confounded:
//  - conv_base = r5-exact tiling (64px, grid 1024) + stage(s+1) issued after
//    tap-8's A-loads (sched_barrier-pinned).
//  - kv_all4 = full-row r16 tiling + double-buffered LDS + per-group A-frag
//    register preload, THEN stage(g+1), then MFMA loop (one barrier/group).
// conv_head / attn / setup unchanged.
// ---------------------------------------------------------------------------

#define HW 16384
#define WIMG 128

typedef unsigned short ushortT;
typedef __attribute__((ext_vector_type(8))) short short8;
typedef __attribute__((ext_vector_type(4))) float floatx4;
typedef __attribute__((ext_vector_type(4))) unsigned uintx4;

// ws layout (float offsets)
constexpr size_t OFF_KV    = 16777216;             // bf16 [3][4][128][HW] channel-major
constexpr size_t OFF_A16   = 29360128;             // bf16 [4][32][130][130][8]
constexpr size_t OFF_B16   = 38012928;             // bf16 [4][28][134][134][8]
constexpr size_t OFF_CWT   = 46057216;             // bf16 wA [9][32][192][8]
constexpr size_t OFF_CB    = OFF_CWT + 221184;     // [3][64] fp32
constexpr size_t OFF_HWT   = OFF_CB + 192;         // bf16 wH [3][72][16][8]
constexpr size_t OFF_QWT   = OFF_HWT + 13824;      // bf16 wQ
constexpr size_t OFF_QB    = OFF_QWT + 8192;       // [64]
constexpr size_t OFF_KVW   = OFF_QB + 64;          // bf16 W_eff group-major [532480]
constexpr size_t OFF_GEO   = OFF_KVW + 266240;     // fp32 [3][3][128]
constexpr size_t OFF_P1WT  = OFF_GEO + 1152;       // bf16 wP1
constexpr size_t OFF_P1B   = OFF_P1WT + 40960;     // [256]

struct P53 { const float* p[53]; };

__device__ inline ushortT f2bf(float f) {
    unsigned u = __float_as_uint(f);
    unsigned r = (u + 0x7FFFu + ((u >> 16) & 1u)) >> 16;
    return (ushortT)r;
}
__device__ inline unsigned packbf(float a, float b) {
    return (unsigned)f2bf(a) | ((unsigned)f2bf(b) << 16);
}
__device__ inline float bf2f(ushortT u) {
    return __uint_as_float((unsigned)u << 16);
}

// async global->LDS 16B: lds dst = wave-uniform base + lane*16
typedef __attribute__((address_space(3))) ushortT lds_us;
typedef __attribute__((address_space(1))) const ushortT glb_us;
__device__ inline void gload_lds16(const ushortT* g, ushortT* ldsbase) {
    __builtin_amdgcn_global_load_lds((glb_us*)g, (lds_us*)ldsbase, 16, 0, 0);
}

// sample-point offsets (pixel units), faithful to torch .view(2,n) reinterpret
__device__ const float c_ox[3][9] = {
    {-1.f, 0.f, 1.f, -1.f, 0.f, 1.f, -1.f, 0.f, 1.f},
    {-1.f, 2.4375f, -1.f, -2.4375f, 1.f, 2.4375f, 1.f, -2.4375f, 0.f},
    {-1.625f, -1.625f, -1.625f, 0.f, -1.625f, 1.625f, 0.f, -1.625f, 0.f}};
__device__ const float c_oy[3][9] = {
    {-1.f, -1.f, -1.f, 0.f, 0.f, 0.f, 1.f, 1.f, 1.f},
    {2.4375f, -1.f, -2.4375f, -1.f, 2.4375f, 1.f, -2.4375f, 1.f, 0.f},
    {0.f, 0.f, 1.625f, 1.625f, -1.625f, 1.625f, 0.f, 1.625f, 1.625f}};

// corner-branch tap tables (16 taps)
__device__ const int tapX_cor[16] = {-1,-1, 2, 3,-1,-1,-3,-2, 1, 1, 2, 3, 1, 1,-3,-2};
__device__ const int tapY_cor[16] = { 2, 3,-1,-1,-3,-2,-1,-1, 2, 3, 1, 1,-3,-2, 1, 1};
__device__ const int tapR_cor[16] = { 4, 5, 2, 2, 0, 1, 2, 2, 4, 5, 3, 3, 0, 1, 3, 3};

__device__ inline float cornw(float off, int X) {
    float f = floorf(off);
    float d = off - f;
    int fi = (int)f;
    return (X == fi) ? (1.f - d) : (X == fi + 1) ? d : 0.f;
}

// ------------- setup: fold BN + transpose weights + pass_a/b borders --------
__global__ __launch_bounds__(256) void setup_kernel(P53 ptrs, float* __restrict__ ws,
                                                    const float* __restrict__ base,
                                                    ushortT* __restrict__ a16,
                                                    ushortT* __restrict__ b16) {
    int i = blockIdx.x * 256 + threadIdx.x;
    const float* const* p = ptrs.p;
    if (i < 1102464) {
        if (i < 442368) {  // bf16 wA[tap][g32][M192][j8], ic = g*8+j
            int tap = i / 49152, r = i % 49152;
            int g = r / 1536, r2 = r % 1536;
            int M = r2 >> 3, j = r2 & 7;
            int br = M >> 6, oc = M & 63, ic = g * 8 + j;
            float v = p[1 + 6 * br][(oc * 256 + ic) * 9 + tap] * p[3 + 6 * br][oc];
            ((ushortT*)(ws + OFF_CWT))[i] = f2bf(v);
            return;
        }
        i -= 442368;
        if (i < 192) {
            int br = i >> 6, oc = i & 63;
            ws[OFF_CB + i] = p[2 + 6 * br][oc] * p[3 + 6 * br][oc] + p[4 + 6 * br][oc];
            return;
        }
        i -= 192;
        if (i < 27648) {  // bf16 wH[br][u72][m16][j8]
            int j = i & 7, m = (i >> 3) & 15, u = (i >> 7) % 72, br = i / 9216;
            int cnt = (br == 1) ? 12 : 3;
            int t = u >> 3, g = u & 7, ic = g * 8 + j;
            const float* hw = (br == 0) ? p[5] : (br == 1) ? p[11] : p[17];
            float v = (m < cnt) ? hw[(m * 64 + ic) * 9 + t] : 0.f;
            ((ushortT*)(ws + OFF_HWT))[i] = f2bf(v);
            return;
        }
        i -= 27648;
        if (i < 16384) {  // bf16 wQ[kk8][sub4][m64][j8]
            int j = i & 7, m = (i >> 3) & 63, sg = i >> 9;
            int k = (sg >> 2) * 32 + (sg & 3) * 8 + j;
            ((ushortT*)(ws + OFF_QWT))[i] = f2bf(p[19][m * 256 + k] * p[21][m]);
            return;
        }
        i -= 16384;
        if (i < 64) { ws[OFF_QB + i] = p[20][i] * p[21][i] + p[22][i]; return; }
        i -= 64;
        if (i < 532480) {  // W_eff bf16 group-major: [br][g][q][sub][m128][j8]
            int br, NQ, NTAP, n, C, i2;
            if (i < 110592)      { br = 0; NQ = 3; NTAP = 9;  n = 9; C = 67; i2 = i; }
            else if (i < 274432) { br = 1; NQ = 4; NTAP = 16; n = 8; C = 76; i2 = i - 110592; }
            else                 { br = 2; NQ = 7; NTAP = 25; n = 9; C = 67; i2 = i - 274432; }
            int gsz = NQ * 4096;
            int g = i2 / gsz, r = i2 % gsz;
            int q = r >> 12, r2 = r & 4095;
            int sub = r2 >> 10, m = (r2 >> 3) & 127, j = r2 & 7;
            int t = q * 4 + sub, c = g * 8 + j;
            float v = 0.f;
            if (t < NTAP && c < C) {
                int X, Y;
                if (br == 0)      { X = t % 3 - 1; Y = t / 3 - 1; }
                else if (br == 1) { X = tapX_cor[t]; Y = tapY_cor[t]; }
                else              { X = t % 5 - 2; Y = t / 5 - 2; }
                const float* wsrc = (m < 64) ? p[23 + 8 * br] : p[27 + 8 * br];
                int mo = (m < 64) ? m : m - 64;
                float sc = (m < 64) ? p[25 + 8 * br][mo] : p[29 + 8 * br][mo];
                int Cn = (C + 2) * n;
                float s = 0.f;
                for (int pp = 0; pp < n; ++pp) {
                    float ww = cornw(c_ox[br][pp], X) * cornw(c_oy[br][pp], Y);
                    if (ww != 0.f) s += ww * wsrc[mo * Cn + c * n + pp];
                }
                v = s * sc;
            }
            ((ushortT*)(ws + OFF_KVW))[i] = f2bf(v);
            return;
        }
        i -= 532480;
        if (i < 1152) {  // geo GA/GB/GC [br][which][128]
            int br = i / 384, rem = i % 384, which = rem >> 7, m = rem & 127;
            int n = (br == 1) ? 8 : 9, C = (br == 1) ? 76 : 67, Cn = (C + 2) * n;
            const float* wsrc = (m < 64) ? p[23 + 8 * br] : p[27 + 8 * br];
            int mo = (m < 64) ? m : m - 64;
            float sc = (m < 64) ? p[25 + 8 * br][mo] : p[29 + 8 * br][mo];
            float bb = (m < 64) ? p[24 + 8 * br][mo] : p[28 + 8 * br][mo];
            float tt = (m < 64) ? p[26 + 8 * br][mo] : p[30 + 8 * br][mo];
            float v = 0.f;
            if (which == 0) {
                for (int pp = 0; pp < n; ++pp) v += wsrc[mo * Cn + C * n + pp];
                v *= sc;
            } else if (which == 1) {
                for (int pp = 0; pp < n; ++pp) v += wsrc[mo * Cn + (C + 1) * n + pp];
                v *= sc;
            } else {
                for (int pp = 0; pp < n; ++pp)
                    v += wsrc[mo * Cn + C * n + pp] * c_ox[br][pp]
                       + wsrc[mo * Cn + (C + 1) * n + pp] * c_oy[br][pp];
                v = v * sc * 0.0078125f + bb * sc + tt;
            }
            ws[OFF_GEO + br * 384 + which * 128 + m] = v;
            return;
        }
        i -= 1152;
        if (i < 81920) {  // bf16 wP1[kk10][sub4][M256][j8], K=320 extended
            int j = i & 7, M = (i >> 3) & 255, sg = i >> 11;
            int k = (sg >> 2) * 32 + (sg & 3) * 8 + j;
            int nh = M >> 6, oc = M & 63;
            float sc = p[49][nh * 64 + oc];
            float v;
            if (k < 256) v = p[47][(nh * 64 + oc) * 272 + k] * sc;
            else {
                int k2 = k - 256, nh2 = k2 >> 4, va = k2 & 15;
                v = (nh2 == nh) ? p[47][(nh * 64 + oc) * 272 + 256 + va] * sc : 0.f;
            }
            ((ushortT*)(ws + OFF_P1WT))[i] = f2bf(v);
            return;
        }
        i -= 81920;
        if (i < 256) { ws[OFF_P1B + i] = p[48][i] * p[49][i] + p[50][i]; }
        return;
    }
    int idx = i - 1102464;
    if (idx < 4 * 32 * 130 * 130) {  // pass A: base -> a16 (pad 1)
        int col = idx % 130, t = idx / 130;
        int row = t % 130; t /= 130;
        int icg = t & 31, b = t >> 5;
        int h = row - 1, w = col - 1;
        unsigned wds[4] = {0u, 0u, 0u, 0u};
        if ((unsigned)h < 128u && (unsigned)w < 128u) {
            const float* s = base + (size_t)(b * 256 + icg * 8) * HW + h * WIMG + w;
            #pragma unroll
            for (int jp = 0; jp < 4; ++jp)
                wds[jp] = packbf(s[(size_t)(2 * jp) * HW], s[(size_t)(2 * jp + 1) * HW]);
        }
        unsigned* d = (unsigned*)(a16 + (size_t)idx * 8);
        d[0] = wds[0]; d[1] = wds[1]; d[2] = wds[2]; d[3] = wds[3];
        return;
    }
    idx -= 4 * 32 * 130 * 130;
    if (idx < 4 * 28 * 134 * 134) {  // b16 3-px apron zero
        int col = idx % 134, row = (idx / 134) % 134;
        if (row < 3 || row >= 131 || col < 3 || col >= 131) {
            unsigned* d = (unsigned*)(b16 + (size_t)idx * 8);
            d[0] = 0u; d[1] = 0u; d[2] = 0u; d[3] = 0u;
        }
    }
}

// ---- conv3x3 base(256) -> 192 feats via 16x16x32 bf16 MFMA -> b16 ----------
// r5 tiling (64px, grid 1024); stage(s+1) issued AFTER tap-8's A-loads so
// per-tap A-consume waits never force-drain the in-flight stage.
__global__ __launch_bounds__(256) void conv_base_mfma(
    const ushortT* __restrict__ a16, const ushortT* __restrict__ wA,
    const float* __restrict__ cb, ushortT* __restrict__ b16)
{
    const int wv = threadIdx.x >> 6, lane = threadIdx.x & 63;
    const int sub = lane >> 4, ln = lane & 15;
    const int xh = blockIdx.x, h = blockIdx.y, b = blockIdx.z;
    const int x0 = xh * 64;
    __shared__ __align__(16) ushortT sbuf[2][792 * 8];

    floatx4 acc[3][4];
    #pragma unroll
    for (int mt = 0; mt < 3; ++mt)
        #pragma unroll
        for (int nt = 0; nt < 4; ++nt)
            #pragma unroll
            for (int r = 0; r < 4; ++r) acc[mt][nt][r] = 0.f;

    const int wbase = threadIdx.x & ~63;
    auto stage = [&](int s, int buf) {
        #pragma unroll
        for (int it = 0; it < 4; ++it) {
            int idx = threadIdx.x + it * 256;
            if (idx < 792) {
                int col = idx % 66, t2 = idx / 66;
                int r = t2 % 3, icg = t2 / 3;
                const ushortT* g = a16 +
                    (((size_t)(b * 32 + s * 4 + icg) * 130 + (h + r)) * 130 + (x0 + col)) * 8;
                gload_lds16(g, &sbuf[buf][(size_t)(it * 256 + wbase) * 8]);
            }
        }
    };
    stage(0, 0);
    for (int s = 0; s < 8; ++s) {
        __syncthreads();
        const ushortT* sb = sbuf[s & 1];
        #pragma unroll
        for (int tap = 0; tap < 9; ++tap) {
            const int ky = tap / 3, kx = tap % 3;
            short8 Bf[4];
            #pragma unroll
            for (int nt = 0; nt < 4; ++nt) {
                int c = nt * 16 + ln + kx;
                Bf[nt] = *(const short8*)(sb + ((sub * 3 + ky) * 66 + c) * 8);
            }
            const int g = s * 4 + sub;
            short8 Af[3];
            #pragma unroll
            for (int mt = 0; mt < 3; ++mt) {
                int m = wv * 48 + mt * 16 + ln;
                Af[mt] = *(const short8*)(wA + (((size_t)tap * 32 + g) * 192 + m) * 8);
            }
            if (tap == 8 && s < 7) {  // after the phase's LAST global A-load
                __builtin_amdgcn_sched_barrier(0);
                stage(s + 1, (s + 1) & 1);
                __builtin_amdgcn_sched_barrier(0);
            }
            #pragma unroll
            for (int mt = 0; mt < 3; ++mt)
                #pragma unroll
                for (int nt = 0; nt < 4; ++nt)
                    acc[mt][nt] = __builtin_amdgcn_mfma_f32_16x16x32_bf16(
                        Af[mt], Bf[nt], acc[mt][nt], 0, 0, 0);
        }
    }
    #pragma unroll
    for (int mt = 0; mt < 3; ++mt) {
        int ocq = wv * 48 + mt * 16 + sub * 4;
        #pragma unroll
        for (int nt = 0; nt < 4; ++nt) {
            int px = x0 + nt * 16 + ln;
            float v0 = fmaxf(acc[mt][nt][0] + cb[ocq + 0], 0.f);
            float v1 = fmaxf(acc[mt][nt][1] + cb[ocq + 1], 0.f);
            float v2 = fmaxf(acc[mt][nt][2] + cb[ocq + 2], 0.f);
            float v3 = fmaxf(acc[mt][nt][3] + cb[ocq + 3], 0.f);
            unsigned lo = packbf(v0, v1), hi = packbf(v2, v3);
            unsigned plo = (unsigned)__shfl_down((int)lo, 16);
            unsigned phi = (unsigned)__shfl_down((int)hi, 16);
            if (!(sub & 1)) {
                int br = ocq >> 6, oc = ocq & 63;
                int grp = ((br == 0) ? 0 : (br == 1) ? 9 : 19) + (oc >> 3);
                uintx4 w = {lo, hi, plo, phi};
                *(uintx4*)(b16 +
                    (((size_t)(b * 28 + grp) * 134 + (h + 3)) * 134 + (px + 3)) * 8) = w;
            }
        }
    }
}

// ---- head 3x3 convs via MFMA, half-row tiles (M=16 padded maps, K=576) -----
__global__ __launch_bounds__(256) void conv_head_mfma(
    const ushortT* __restrict__ b16c, const ushortT* __restrict__ wH,
    const float* __restrict__ chb, const float* __restrict__ ohb,
    const float* __restrict__ fhb, float* __restrict__ out,
    ushortT* __restrict__ b16)
{
    const int wv = threadIdx.x >> 6, lane = threadIdx.x & 63;
    const int sub = lane >> 4, ln = lane & 15;
    const int x0 = (blockIdx.x & 1) * 64, h = blockIdx.x >> 1;
    const int br = blockIdx.y % 3, b = blockIdx.y / 3;
    const int cnt = (br == 1) ? 12 : 3;
    const int mapb = (br == 0) ? 0 : (br == 1) ? 3 : 15;
    const int grpb = (br == 0) ? 0 : (br == 1) ? 9 : 19;
    const float* bias = (br == 0) ? chb : (br == 1) ? ohb : fhb;
    __shared__ __align__(16) ushortT sbuf[8 * 3 * 66 * 8];  // 25,344 B
    const int wbase = threadIdx.x & ~63;

    for (int it = 0; it < 7; ++it) {
        int idx = threadIdx.x + it * 256;
        if (idx < 1584) {
            int col = idx % 66, t2 = idx / 66;
            int r = t2 % 3, g = t2 / 3;
            const ushortT* gp = b16c +
                (((size_t)(b * 28 + grpb + g) * 134 + (h + r + 2)) * 134 + (x0 + col + 2)) * 8;
            gload_lds16(gp, sbuf + (size_t)(it * 256 + wbase) * 8);
        }
    }
    __syncthreads();

    floatx4 acc;
    #pragma unroll
    for (int r = 0; r < 4; ++r) acc[r] = 0.f;
    #pragma unroll
    for (int k = 0; k < 18; ++k) {
        int u = k * 4 + sub;
        int t = u >> 3, g = u & 7;
        int dxv = t % 3 - 1, ry = t / 3;
        short8 Af = *(const short8*)(wH + ((size_t)(br * 72 + u) * 16 + ln) * 8);
        int c = wv * 16 + ln + dxv + 1;
        short8 Bf = *(const short8*)(sbuf + ((g * 3 + ry) * 66 + c) * 8);
        acc = __builtin_amdgcn_mfma_f32_16x16x32_bf16(Af, Bf, acc, 0, 0, 0);
    }
    {
        int px = x0 + wv * 16 + ln;
        #pragma unroll
        for (int r = 0; r < 4; ++r) {
            int m = sub * 4 + r;
            if (m < cnt) {
                float v = acc[r] + bias[m];
                out[((size_t)b * 26 + mapb + m) * HW + h * WIMG + px] = v;
                int grp = grpb + 8 + (m >> 3), j = m & 7;
                b16[(((size_t)(b * 28 + grp) * 134 + (h + 3)) * 134 + (px + 3)) * 8 + j]
                    = f2bf(v);
            }
        }
    }
}

// ------ kv: full-row N=128, double-buffered, A-preload + late stage ---------
template<int BRV>
__device__ __forceinline__ void kv_body(
    const ushortT* __restrict__ b16, const ushortT* __restrict__ kvw,
    const float* __restrict__ geob, ushortT* __restrict__ kvout,
    ushortT* __restrict__ sbufRaw, int h, int b)
{
    constexpr int NG   = (BRV == 0) ? 9 : (BRV == 1) ? 10 : 9;   // channel groups
    constexpr int NTAP = (BRV == 0) ? 9 : (BRV == 1) ? 16 : 25;
    constexpr int NQ   = (BRV == 0) ? 3 : (BRV == 1) ? 4 : 7;    // tap quads (padded)
    constexpr int ROWS = (BRV == 0) ? 3 : (BRV == 1) ? 6 : 5;
    constexpr int COLS = (BRV == 0) ? 130 : (BRV == 1) ? 134 : 132;  // 128 + x-apron
    constexpr int XMIN = (BRV == 0) ? -1 : (BRV == 1) ? -3 : -2;
    constexpr int UBASE = (BRV == 0) ? 0 : (BRV == 1) ? 9 : 19;
    constexpr int NEL  = ROWS * COLS;            // 390 / 804 / 660 per group
    constexpr int NIT  = (NEL + 255) / 256;
    constexpr int WBASE = (BRV == 0) ? 0 : (BRV == 1) ? 110592 : 274432;  // ushorts

    const int lane = threadIdx.x & 63, wv = threadIdx.x >> 6;
    const int sub = lane >> 4, ln = lane & 15;
    const int wbase = threadIdx.x & ~63;
    const int thrB = ln * 16;

    // per-quad B byte offsets within the full-row group tile
    int boff[NQ];
    #pragma unroll
    for (int q = 0; q < NQ; ++q) {
        int t = q * 4 + sub;
        int dxv, ry;
        if (t >= NTAP)          { dxv = -XMIN; ry = 0; }  // padded tap: zero wt, safe addr
        else if (BRV == 0)      { dxv = t % 3 - 1; ry = t / 3; }
        else if (BRV == 1)      { dxv = tapX_cor[t]; ry = tapR_cor[t]; }
        else                    { dxv = t % 5 - 2; ry = t / 5; }
        boff[q] = (ry * COLS + (dxv - XMIN)) * 16 + thrB;
    }

    auto stage = [&](int g, int buf) {
        #pragma unroll
        for (int it = 0; it < NIT; ++it) {
            int idx = threadIdx.x + it * 256;
            if (idx < NEL) {
                int rw = idx / COLS, col = idx % COLS;
                int dy = (BRV == 1) ? ((rw < 3) ? rw - 3 : rw - 2) : (rw - ROWS / 2);
                const ushortT* gp = b16 +
                    (((size_t)(b * 28 + UBASE + g) * 134 + (h + dy + 3)) * 134
                     + (col + XMIN + 3)) * 8;
                gload_lds16(gp, sbufRaw + (size_t)buf * (NEL * 8)
                                        + (size_t)(it * 256 + wbase) * 8);
            }
        }
    };

    floatx4 acc[2][8];
    #pragma unroll
    for (int mt = 0; mt < 2; ++mt)
        #pragma unroll
        for (int nt = 0; nt < 8; ++nt)
            #pragma unroll
            for (int r = 0; r < 4; ++r) acc[mt][nt][r] = 0.f;

    const ushortT* wp0 = kvw + WBASE + (size_t)sub * 1024 + (wv * 32 + ln) * 8;

    stage(0, 0);
    int cur = 0;
    for (int g = 0; g < NG; ++g) {
        // drains stage(g) (vmcnt0 in barrier) and separates phase g-1 reads
        // from the stage(g+1) issue below (so dbuf WAR is safe).
        __syncthreads();
        const char* sb8 = (const char*)(sbufRaw + (size_t)cur * (NEL * 8));
        const ushortT* wg = wp0 + (size_t)g * (NQ * 4096);

        // preload ALL A fragments for this group (registers, static-indexed)
        short8 Areg[NQ][2];
        #pragma unroll
        for (int q = 0; q < NQ; ++q) {
            Areg[q][0] = *(const short8*)(wg + (size_t)q * 4096);
            Areg[q][1] = *(const short8*)(wg + (size_t)q * 4096 + 128);
        }
        // now (and only now) issue next-group stage: A-waits above precede it
        // in issue order, so waiting on A never drains the stage.
        if (g + 1 < NG) {
            __builtin_amdgcn_sched_barrier(0);
            stage(g + 1, cur ^ 1);
            __builtin_amdgcn_sched_barrier(0);
        }
        #pragma unroll
        for (int q = 0; q < NQ; ++q) {
            int bb = boff[q];
            #pragma unroll
            for (int nt = 0; nt < 8; ++nt) {
                short8 Bf = *(const short8*)(sb8 + bb + nt * 256);
                acc[0][nt] = __builtin_amdgcn_mfma_f32_16x16x32_bf16(
                    Areg[q][0], Bf, acc[0][nt], 0, 0, 0);
                acc[1][nt] = __builtin_amdgcn_mfma_f32_16x16x32_bf16(
                    Areg[q][1], Bf, acc[1][nt], 0, 0, 0);
            }
        }
        cur ^= 1;
    }

    // epilogue: + GA*fx + GB*fy + GC, relu, channel-major bf16 (full 256B lines)
    const float* geo = geob + BRV * 384;
    const float fy = (h + 0.5f) * 0.0078125f;
    #pragma unroll
    for (int mt = 0; mt < 2; ++mt)
        #pragma unroll
        for (int nt = 0; nt < 8; ++nt) {
            int px = nt * 16 + ln;
            float fx = (px + 0.5f) * 0.0078125f;
            #pragma unroll
            for (int r = 0; r < 4; ++r) {
                int Mi = wv * 32 + mt * 16 + sub * 4 + r;
                float v = acc[mt][nt][r] + geo[Mi] * fx + geo[128 + Mi] * fy + geo[256 + Mi];
                kvout[((size_t)(BRV * 4 + b) * 128 + Mi) * HW + h * WIMG + px] =
                    f2bf(fmaxf(v, 0.f));
            }
        }
}

__global__ __launch_bounds__(256, 3) void kv_all4(
    const ushortT* __restrict__ b16, const ushortT* __restrict__ kvw,
    const float* __restrict__ geob, ushortT* __restrict__ kvout)
{
    __shared__ __align__(16) ushortT sbuf[2 * 804 * 8];  // dbuf, union max (br1)
    const int h = blockIdx.x;
    const int z = blockIdx.y;            // brv*4 + b
    const int brv = z >> 2, b = z & 3;
    if (brv == 0)      kv_body<0>(b16, kvw, geob, kvout, sbuf, h, b);
    else if (brv == 1) kv_body<1>(b16, kvw, geob, kvout, sbuf, h, b);
    else               kv_body<2>(b16, kvw, geob, kvout, sbuf, h, b);
}

// -------- fused q-GEMM + attention softmax + p1(MFMA,K=320) + p2 ------------
__global__ __launch_bounds__(256) void attn_pred_mfma(
    float* __restrict__ ws, const float* __restrict__ p2w,
    const float* __restrict__ p2b, float* __restrict__ out)
{
    const int wv = threadIdx.x >> 6, lane = threadIdx.x & 63;
    const int sub = lane >> 4, ln = lane & 15;
    const int px0 = blockIdx.x * 64, b = blockIdx.y;
    const ushortT* wP1 = (const ushortT*)(ws + OFF_P1WT);
    const ushortT* wQ  = (const ushortT*)(ws + OFF_QWT);
    const ushortT* a16 = (const ushortT*)(ws + OFF_A16);
    const ushortT* kv = (const ushortT*)(ws + OFF_KV);
    const float* p1b = ws + OFF_P1B;
    const float* qb  = ws + OFF_QB;
    __shared__ __align__(16) ushortT xbuf[40 * 64 * 8];
    __shared__ __align__(16) ushortT qld[64 * 64];

    const int mypx = threadIdx.x & 63, nh = threadIdx.x >> 6;
    const int gpx = px0 + mypx, hh = gpx >> 7, ww = gpx & 127;
    #pragma unroll
    for (int g2 = 0; g2 < 8; ++g2) {
        int g = nh * 8 + g2;
        const ushortT* gp = a16 +
            (((size_t)(b * 32 + g) * 130 + (hh + 1)) * 130 + (ww + 1)) * 8;
        gload_lds16(gp, xbuf + (size_t)g * 64 * 8);
    }
    __syncthreads();

    {
        floatx4 qacc[4];
        #pragma unroll
        for (int nt = 0; nt < 4; ++nt)
            #pragma unroll
            for (int r = 0; r < 4; ++r) qacc[nt][r] = 0.f;
        #pragma unroll
        for (int kk = 0; kk < 8; ++kk) {
            short8 Af = *(const short8*)(wQ + (((kk * 4 + sub) * 64) + wv * 16 + ln) * 8);
            #pragma unroll
            for (int nt = 0; nt < 4; ++nt) {
                short8 Bf = *(const short8*)(xbuf + (((kk * 4 + sub) * 64) + nt * 16 + ln) * 8);
                qacc[nt] = __builtin_amdgcn_mfma_f32_16x16x32_bf16(Af, Bf, qacc[nt], 0, 0, 0);
            }
        }
        #pragma unroll
        for (int nt = 0; nt < 4; ++nt)
            #pragma unroll
            for (int r = 0; r < 4; ++r) {
                int row = wv * 16 + sub * 4 + r;
                qld[row * 64 + nt * 16 + ln] = f2bf(fmaxf(qacc[nt][r] + qb[row], 0.f));
            }
    }
    __syncthreads();

    {
        float l[3];
        #pragma unroll
        for (int br = 0; br < 3; ++br) {
            float s = 0.f;
            #pragma unroll
            for (int ko = 0; ko < 16; ++ko)
                s = fmaf(bf2f(qld[(nh * 16 + ko) * 64 + mypx]),
                         bf2f(kv[(size_t)((br * 4 + b) * 128 + nh * 16 + ko) * HW + gpx]), s);
            l[br] = s;
        }
        float m = fmaxf(l[0], fmaxf(l[1], l[2]));
        float e0 = __expf(l[0] - m), e1 = __expf(l[1] - m), e2 = __expf(l[2] - m);
        float inv = 1.f / (e0 + e1 + e2);
        float aw0 = e0 * inv, aw1 = e1 * inv, aw2 = e2 * inv;
        #pragma unroll
        for (int vap = 0; vap < 8; ++vap) {
            int va0 = vap * 2, va1 = vap * 2 + 1;
            float a0 =
                aw0 * bf2f(kv[(size_t)((0 * 4 + b) * 128 + 64 + nh * 16 + va0) * HW + gpx]) +
                aw1 * bf2f(kv[(size_t)((1 * 4 + b) * 128 + 64 + nh * 16 + va0) * HW + gpx]) +
                aw2 * bf2f(kv[(size_t)((2 * 4 + b) * 128 + 64 + nh * 16 + va0) * HW + gpx]);
            float a1 =
                aw0 * bf2f(kv[(size_t)((0 * 4 + b) * 128 + 64 + nh * 16 + va1) * HW + gpx]) +
                aw1 * bf2f(kv[(size_t)((1 * 4 + b) * 128 + 64 + nh * 16 + va1) * HW + gpx]) +
                aw2 * bf2f(kv[(size_t)((2 * 4 + b) * 128 + 64 + nh * 16 + va1) * HW + gpx]);
            int g = 32 + nh * 2 + (vap >> 2), wo = vap & 3;
            ((unsigned*)xbuf)[(g * 64 + mypx) * 4 + wo] = packbf(a0, a1);
        }
    }
    __syncthreads();

    floatx4 acc[4][4];
    #pragma unroll
    for (int mt = 0; mt < 4; ++mt)
        #pragma unroll
        for (int nt = 0; nt < 4; ++nt)
            #pragma unroll
            for (int r = 0; r < 4; ++r) acc[mt][nt][r] = 0.f;
    #pragma unroll
    for (int kk = 0; kk < 10; ++kk) {
        short8 Bf[4];
        #pragma unroll
        for (int nt = 0; nt < 4; ++nt)
            Bf[nt] = *(const short8*)(xbuf + (((kk * 4 + sub) * 64) + nt * 16 + ln) * 8);
        #pragma unroll
        for (int mt = 0; mt < 4; ++mt) {
            short8 Af = *(const short8*)(wP1 +
                (((size_t)(kk * 4 + sub) * 256) + wv * 64 + mt * 16 + ln) * 8);
            #pragma unroll
            for (int nt = 0; nt < 4; ++nt)
                acc[mt][nt] = __builtin_amdgcn_mfma_f32_16x16x32_bf16(Af, Bf[nt], acc[mt][nt], 0, 0, 0);
        }
    }

    float po0[4] = {0.f, 0.f, 0.f, 0.f}, po1[4] = {0.f, 0.f, 0.f, 0.f};
    #pragma unroll
    for (int mt = 0; mt < 4; ++mt)
        #pragma unroll
        for (int r = 0; r < 4; ++r) {
            int oc = mt * 16 + sub * 4 + r;
            float bias = p1b[wv * 64 + oc];
            float w0 = p2w[(wv * 2 + 0) * 64 + oc];
            float w1 = p2w[(wv * 2 + 1) * 64 + oc];
            #pragma unroll
            for (int nt = 0; nt < 4; ++nt) {
                float hv = fmaxf(acc[mt][nt][r] + bias, 0.f);
                po0[nt] = fmaf(w0, hv, po0[nt]);
                po1[nt] = fmaf(w1, hv, po1[nt]);
            }
        }
    #pragma unroll
    for (int nt = 0; nt < 4; ++nt) {
        po0[nt] += __shfl_xor(po0[nt], 16);
        po0[nt] += __shfl_xor(po0[nt], 32);
        po1[nt] += __shfl_xor(po1[nt], 16);
        po1[nt] += __shfl_xor(po1[nt], 32);
    }
    if (sub == 0) {
        #pragma unroll
        for (int nt = 0; nt < 4; ++nt) {
            int px = px0 + nt * 16 + ln;
            out[((size_t)b * 26 + 18 + wv * 2 + 0) * HW + px] = po0[nt] + p2b[wv * 2 + 0];
            out[((size_t)b * 26 + 18 + wv * 2 + 1) * HW + px] = po1[nt] + p2b[wv * 2 + 1];
        }
    }
}

// ---------------------------------------------------------------------------
extern "C" void kernel_launch(void* const* d_in, const int* in_sizes, int n_in,
                              void* d_out, int out_size, void* d_ws, size_t ws_size,
                              hipStream_t stream) {
    (void)in_sizes; (void)n_in; (void)out_size; (void)ws_size;
    float* ws  = (float*)d_ws;
    float* out = (float*)d_out;
    const float* base = (const float*)d_in[0];
    P53 ptrs;
    for (int i = 0; i < 53; ++i) ptrs.p[i] = (const float*)d_in[i];

    ushortT* a16 = (ushortT*)(ws + OFF_A16);
    ushortT* b16 = (ushortT*)(ws + OFF_B16);
    ushortT* kvb = (ushortT*)(ws + OFF_KV);
    const ushortT* kvw = (const ushortT*)(ws + OFF_KVW);

    setup_kernel<<<20613, 256, 0, stream>>>(ptrs, ws, base, a16, b16);
    conv_base_mfma<<<dim3(2, 128, 4), 256, 0, stream>>>(
        a16, (const ushortT*)(ws + OFF_CWT), ws + OFF_CB, b16);
    conv_head_mfma<<<dim3(256, 12), 256, 0, stream>>>(
        b16, (const ushortT*)(ws + OFF_HWT),
        (const float*)d_in[6], (const float*)d_in[12], (const float*)d_in[18],
        out, b16);
    kv_all4<<<dim3(128, 12), 256, 0, stream>>>(b16, kvw, ws + OFF_GEO, kvb);
    attn_pred_mfma<<<dim3(256, 4), 256, 0, stream>>>(ws, (const float*)d_in[51],
                                                     (const float*)d_in[52], out);
}

// Round 8
// 395.278 us; speedup vs baseline: 1.1146x; 1.0411x over previous
//
#include <hip/hip_runtime.h>
#include <hip/hip_bf16.h>
#include <math.h>

// ---------------------------------------------------------------------------
// HydraFusionHead: B=4, IN_CH=256, HEAD_CH=64, H=W=128, NH=4, KEY=VAL=16
// Round-19: conv_base -> 8-wave (512-thread) full-row blocks. Per-wave code is
// r5-exact (acc[3][4], ~80 VGPR): wave w = (nh=w>>2 N-half, wv=w&3 M-slice).
// Twin waves (same wv, nh 0/1) issue identical A-loads on the same CU at the
// same time -> L1 dedup halves L2 A-panel traffic (884->~442 MB); full-row
// stage (25KB/phase, dbuf 49.9KB) amortizes over 2x MFMA per barrier; 512
// blocks. Late stage (tap==8) retained. kv_all4 (r18 preload+latestage+dbuf),
// conv_head, attn, setup unchanged.
// ---------------------------------------------------------------------------

#define HW 16384
#define WIMG 128

typedef unsigned short ushortT;
typedef __attribute__((ext_vector_type(8))) short short8;
typedef __attribute__((ext_vector_type(4))) float floatx4;
typedef __attribute__((ext_vector_type(4))) unsigned uintx4;

// ws layout (float offsets)
constexpr size_t OFF_KV    = 16777216;             // bf16 [3][4][128][HW] channel-major
constexpr size_t OFF_A16   = 29360128;             // bf16 [4][32][130][130][8]
constexpr size_t OFF_B16   = 38012928;             // bf16 [4][28][134][134][8]
constexpr size_t OFF_CWT   = 46057216;             // bf16 wA [9][32][192][8]
constexpr size_t OFF_CB    = OFF_CWT + 221184;     // [3][64] fp32
constexpr size_t OFF_HWT   = OFF_CB + 192;         // bf16 wH [3][72][16][8]
constexpr size_t OFF_QWT   = OFF_HWT + 13824;      // bf16 wQ
constexpr size_t OFF_QB    = OFF_QWT + 8192;       // [64]
constexpr size_t OFF_KVW   = OFF_QB + 64;          // bf16 W_eff group-major [532480]
constexpr size_t OFF_GEO   = OFF_KVW + 266240;     // fp32 [3][3][128]
constexpr size_t OFF_P1WT  = OFF_GEO + 1152;       // bf16 wP1
constexpr size_t OFF_P1B   = OFF_P1WT + 40960;     // [256]

struct P53 { const float* p[53]; };

__device__ inline ushortT f2bf(float f) {
    unsigned u = __float_as_uint(f);
    unsigned r = (u + 0x7FFFu + ((u >> 16) & 1u)) >> 16;
    return (ushortT)r;
}
__device__ inline unsigned packbf(float a, float b) {
    return (unsigned)f2bf(a) | ((unsigned)f2bf(b) << 16);
}
__device__ inline float bf2f(ushortT u) {
    return __uint_as_float((unsigned)u << 16);
}

// async global->LDS 16B: lds dst = wave-uniform base + lane*16
typedef __attribute__((address_space(3))) ushortT lds_us;
typedef __attribute__((address_space(1))) const ushortT glb_us;
__device__ inline void gload_lds16(const ushortT* g, ushortT* ldsbase) {
    __builtin_amdgcn_global_load_lds((glb_us*)g, (lds_us*)ldsbase, 16, 0, 0);
}

// sample-point offsets (pixel units), faithful to torch .view(2,n) reinterpret
__device__ const float c_ox[3][9] = {
    {-1.f, 0.f, 1.f, -1.f, 0.f, 1.f, -1.f, 0.f, 1.f},
    {-1.f, 2.4375f, -1.f, -2.4375f, 1.f, 2.4375f, 1.f, -2.4375f, 0.f},
    {-1.625f, -1.625f, -1.625f, 0.f, -1.625f, 1.625f, 0.f, -1.625f, 0.f}};
__device__ const float c_oy[3][9] = {
    {-1.f, -1.f, -1.f, 0.f, 0.f, 0.f, 1.f, 1.f, 1.f},
    {2.4375f, -1.f, -2.4375f, -1.f, 2.4375f, 1.f, -2.4375f, 1.f, 0.f},
    {0.f, 0.f, 1.625f, 1.625f, -1.625f, 1.625f, 0.f, 1.625f, 1.625f}};

// corner-branch tap tables (16 taps)
__device__ const int tapX_cor[16] = {-1,-1, 2, 3,-1,-1,-3,-2, 1, 1, 2, 3, 1, 1,-3,-2};
__device__ const int tapY_cor[16] = { 2, 3,-1,-1,-3,-2,-1,-1, 2, 3, 1, 1,-3,-2, 1, 1};
__device__ const int tapR_cor[16] = { 4, 5, 2, 2, 0, 1, 2, 2, 4, 5, 3, 3, 0, 1, 3, 3};

__device__ inline float cornw(float off, int X) {
    float f = floorf(off);
    float d = off - f;
    int fi = (int)f;
    return (X == fi) ? (1.f - d) : (X == fi + 1) ? d : 0.f;
}

// ------------- setup: fold BN + transpose weights + pass_a/b borders --------
__global__ __launch_bounds__(256) void setup_kernel(P53 ptrs, float* __restrict__ ws,
                                                    const float* __restrict__ base,
                                                    ushortT* __restrict__ a16,
                                                    ushortT* __restrict__ b16) {
    int i = blockIdx.x * 256 + threadIdx.x;
    const float* const* p = ptrs.p;
    if (i < 1102464) {
        if (i < 442368) {  // bf16 wA[tap][g32][M192][j8], ic = g*8+j
            int tap = i / 49152, r = i % 49152;
            int g = r / 1536, r2 = r % 1536;
            int M = r2 >> 3, j = r2 & 7;
            int br = M >> 6, oc = M & 63, ic = g * 8 + j;
            float v = p[1 + 6 * br][(oc * 256 + ic) * 9 + tap] * p[3 + 6 * br][oc];
            ((ushortT*)(ws + OFF_CWT))[i] = f2bf(v);
            return;
        }
        i -= 442368;
        if (i < 192) {
            int br = i >> 6, oc = i & 63;
            ws[OFF_CB + i] = p[2 + 6 * br][oc] * p[3 + 6 * br][oc] + p[4 + 6 * br][oc];
            return;
        }
        i -= 192;
        if (i < 27648) {  // bf16 wH[br][u72][m16][j8]
            int j = i & 7, m = (i >> 3) & 15, u = (i >> 7) % 72, br = i / 9216;
            int cnt = (br == 1) ? 12 : 3;
            int t = u >> 3, g = u & 7, ic = g * 8 + j;
            const float* hw = (br == 0) ? p[5] : (br == 1) ? p[11] : p[17];
            float v = (m < cnt) ? hw[(m * 64 + ic) * 9 + t] : 0.f;
            ((ushortT*)(ws + OFF_HWT))[i] = f2bf(v);
            return;
        }
        i -= 27648;
        if (i < 16384) {  // bf16 wQ[kk8][sub4][m64][j8]
            int j = i & 7, m = (i >> 3) & 63, sg = i >> 9;
            int k = (sg >> 2) * 32 + (sg & 3) * 8 + j;
            ((ushortT*)(ws + OFF_QWT))[i] = f2bf(p[19][m * 256 + k] * p[21][m]);
            return;
        }
        i -= 16384;
        if (i < 64) { ws[OFF_QB + i] = p[20][i] * p[21][i] + p[22][i]; return; }
        i -= 64;
        if (i < 532480) {  // W_eff bf16 group-major: [br][g][q][sub][m128][j8]
            int br, NQ, NTAP, n, C, i2;
            if (i < 110592)      { br = 0; NQ = 3; NTAP = 9;  n = 9; C = 67; i2 = i; }
            else if (i < 274432) { br = 1; NQ = 4; NTAP = 16; n = 8; C = 76; i2 = i - 110592; }
            else                 { br = 2; NQ = 7; NTAP = 25; n = 9; C = 67; i2 = i - 274432; }
            int gsz = NQ * 4096;
            int g = i2 / gsz, r = i2 % gsz;
            int q = r >> 12, r2 = r & 4095;
            int sub = r2 >> 10, m = (r2 >> 3) & 127, j = r2 & 7;
            int t = q * 4 + sub, c = g * 8 + j;
            float v = 0.f;
            if (t < NTAP && c < C) {
                int X, Y;
                if (br == 0)      { X = t % 3 - 1; Y = t / 3 - 1; }
                else if (br == 1) { X = tapX_cor[t]; Y = tapY_cor[t]; }
                else              { X = t % 5 - 2; Y = t / 5 - 2; }
                const float* wsrc = (m < 64) ? p[23 + 8 * br] : p[27 + 8 * br];
                int mo = (m < 64) ? m : m - 64;
                float sc = (m < 64) ? p[25 + 8 * br][mo] : p[29 + 8 * br][mo];
                int Cn = (C + 2) * n;
                float s = 0.f;
                for (int pp = 0; pp < n; ++pp) {
                    float ww = cornw(c_ox[br][pp], X) * cornw(c_oy[br][pp], Y);
                    if (ww != 0.f) s += ww * wsrc[mo * Cn + c * n + pp];
                }
                v = s * sc;
            }
            ((ushortT*)(ws + OFF_KVW))[i] = f2bf(v);
            return;
        }
        i -= 532480;
        if (i < 1152) {  // geo GA/GB/GC [br][which][128]
            int br = i / 384, rem = i % 384, which = rem >> 7, m = rem & 127;
            int n = (br == 1) ? 8 : 9, C = (br == 1) ? 76 : 67, Cn = (C + 2) * n;
            const float* wsrc = (m < 64) ? p[23 + 8 * br] : p[27 + 8 * br];
            int mo = (m < 64) ? m : m - 64;
            float sc = (m < 64) ? p[25 + 8 * br][mo] : p[29 + 8 * br][mo];
            float bb = (m < 64) ? p[24 + 8 * br][mo] : p[28 + 8 * br][mo];
            float tt = (m < 64) ? p[26 + 8 * br][mo] : p[30 + 8 * br][mo];
            float v = 0.f;
            if (which == 0) {
                for (int pp = 0; pp < n; ++pp) v += wsrc[mo * Cn + C * n + pp];
                v *= sc;
            } else if (which == 1) {
                for (int pp = 0; pp < n; ++pp) v += wsrc[mo * Cn + (C + 1) * n + pp];
                v *= sc;
            } else {
                for (int pp = 0; pp < n; ++pp)
                    v += wsrc[mo * Cn + C * n + pp] * c_ox[br][pp]
                       + wsrc[mo * Cn + (C + 1) * n + pp] * c_oy[br][pp];
                v = v * sc * 0.0078125f + bb * sc + tt;
            }
            ws[OFF_GEO + br * 384 + which * 128 + m] = v;
            return;
        }
        i -= 1152;
        if (i < 81920) {  // bf16 wP1[kk10][sub4][M256][j8], K=320 extended
            int j = i & 7, M = (i >> 3) & 255, sg = i >> 11;
            int k = (sg >> 2) * 32 + (sg & 3) * 8 + j;
            int nh = M >> 6, oc = M & 63;
            float sc = p[49][nh * 64 + oc];
            float v;
            if (k < 256) v = p[47][(nh * 64 + oc) * 272 + k] * sc;
            else {
                int k2 = k - 256, nh2 = k2 >> 4, va = k2 & 15;
                v = (nh2 == nh) ? p[47][(nh * 64 + oc) * 272 + 256 + va] * sc : 0.f;
            }
            ((ushortT*)(ws + OFF_P1WT))[i] = f2bf(v);
            return;
        }
        i -= 81920;
        if (i < 256) { ws[OFF_P1B + i] = p[48][i] * p[49][i] + p[50][i]; }
        return;
    }
    int idx = i - 1102464;
    if (idx < 4 * 32 * 130 * 130) {  // pass A: base -> a16 (pad 1)
        int col = idx % 130, t = idx / 130;
        int row = t % 130; t /= 130;
        int icg = t & 31, b = t >> 5;
        int h = row - 1, w = col - 1;
        unsigned wds[4] = {0u, 0u, 0u, 0u};
        if ((unsigned)h < 128u && (unsigned)w < 128u) {
            const float* s = base + (size_t)(b * 256 + icg * 8) * HW + h * WIMG + w;
            #pragma unroll
            for (int jp = 0; jp < 4; ++jp)
                wds[jp] = packbf(s[(size_t)(2 * jp) * HW], s[(size_t)(2 * jp + 1) * HW]);
        }
        unsigned* d = (unsigned*)(a16 + (size_t)idx * 8);
        d[0] = wds[0]; d[1] = wds[1]; d[2] = wds[2]; d[3] = wds[3];
        return;
    }
    idx -= 4 * 32 * 130 * 130;
    if (idx < 4 * 28 * 134 * 134) {  // b16 3-px apron zero
        int col = idx % 134, row = (idx / 134) % 134;
        if (row < 3 || row >= 131 || col < 3 || col >= 131) {
            unsigned* d = (unsigned*)(b16 + (size_t)idx * 8);
            d[0] = 0u; d[1] = 0u; d[2] = 0u; d[3] = 0u;
        }
    }
}

// ---- conv3x3 base(256) -> 192 feats via 16x16x32 bf16 MFMA -> b16 ----------
// 8-wave full-row blocks: wave w = (nh=w>>2 N-half, wv=w&3 M-slice); per-wave
// code r5-exact. Twin waves' identical A-loads dedup in L1. Late stage.
__global__ __launch_bounds__(512) void conv_base_mfma(
    const ushortT* __restrict__ a16, const ushortT* __restrict__ wA,
    const float* __restrict__ cb, ushortT* __restrict__ b16)
{
    const int w = threadIdx.x >> 6, lane = threadIdx.x & 63;
    const int wv = w & 3, nh = w >> 2;
    const int sub = lane >> 4, ln = lane & 15;
    const int h = blockIdx.x, b = blockIdx.y;
    const int x0 = nh * 64;
    __shared__ __align__(16) ushortT sbuf[2][1560 * 8];  // 49,920 B

    floatx4 acc[3][4];
    #pragma unroll
    for (int mt = 0; mt < 3; ++mt)
        #pragma unroll
        for (int nt = 0; nt < 4; ++nt)
            #pragma unroll
            for (int r = 0; r < 4; ++r) acc[mt][nt][r] = 0.f;

    const int wbase = threadIdx.x & ~63;
    auto stage = [&](int s, int buf) {
        #pragma unroll
        for (int it = 0; it < 4; ++it) {
            int idx = threadIdx.x + it * 512;
            if (idx < 1560) {
                int col = idx % 130, t2 = idx / 130;
                int r = t2 % 3, icg = t2 / 3;
                const ushortT* g = a16 +
                    (((size_t)(b * 32 + s * 4 + icg) * 130 + (h + r)) * 130 + col) * 8;
                gload_lds16(g, &sbuf[buf][(size_t)(it * 512 + wbase) * 8]);
            }
        }
    };
    stage(0, 0);
    for (int s = 0; s < 8; ++s) {
        __syncthreads();
        const ushortT* sb = sbuf[s & 1];
        #pragma unroll
        for (int tap = 0; tap < 9; ++tap) {
            const int ky = tap / 3, kx = tap % 3;
            short8 Bf[4];
            #pragma unroll
            for (int nt = 0; nt < 4; ++nt) {
                int c = x0 + nt * 16 + ln + kx;
                Bf[nt] = *(const short8*)(sb + ((sub * 3 + ky) * 130 + c) * 8);
            }
            const int g = s * 4 + sub;
            short8 Af[3];
            #pragma unroll
            for (int mt = 0; mt < 3; ++mt) {
                int m = wv * 48 + mt * 16 + ln;
                Af[mt] = *(const short8*)(wA + (((size_t)tap * 32 + g) * 192 + m) * 8);
            }
            if (tap == 8 && s < 7) {  // after the phase's LAST global A-load
                __builtin_amdgcn_sched_barrier(0);
                stage(s + 1, (s + 1) & 1);
                __builtin_amdgcn_sched_barrier(0);
            }
            #pragma unroll
            for (int mt = 0; mt < 3; ++mt)
                #pragma unroll
                for (int nt = 0; nt < 4; ++nt)
                    acc[mt][nt] = __builtin_amdgcn_mfma_f32_16x16x32_bf16(
                        Af[mt], Bf[nt], acc[mt][nt], 0, 0, 0);
        }
    }
    #pragma unroll
    for (int mt = 0; mt < 3; ++mt) {
        int ocq = wv * 48 + mt * 16 + sub * 4;
        #pragma unroll
        for (int nt = 0; nt < 4; ++nt) {
            int px = x0 + nt * 16 + ln;
            float v0 = fmaxf(acc[mt][nt][0] + cb[ocq + 0], 0.f);
            float v1 = fmaxf(acc[mt][nt][1] + cb[ocq + 1], 0.f);
            float v2 = fmaxf(acc[mt][nt][2] + cb[ocq + 2], 0.f);
            float v3 = fmaxf(acc[mt][nt][3] + cb[ocq + 3], 0.f);
            unsigned lo = packbf(v0, v1), hi = packbf(v2, v3);
            unsigned plo = (unsigned)__shfl_down((int)lo, 16);
            unsigned phi = (unsigned)__shfl_down((int)hi, 16);
            if (!(sub & 1)) {
                int br = ocq >> 6, oc = ocq & 63;
                int grp = ((br == 0) ? 0 : (br == 1) ? 9 : 19) + (oc >> 3);
                uintx4 wd = {lo, hi, plo, phi};
                *(uintx4*)(b16 +
                    (((size_t)(b * 28 + grp) * 134 + (h + 3)) * 134 + (px + 3)) * 8) = wd;
            }
        }
    }
}

// ---- head 3x3 convs via MFMA, half-row tiles (M=16 padded maps, K=576) -----
__global__ __launch_bounds__(256) void conv_head_mfma(
    const ushortT* __restrict__ b16c, const ushortT* __restrict__ wH,
    const float* __restrict__ chb, const float* __restrict__ ohb,
    const float* __restrict__ fhb, float* __restrict__ out,
    ushortT* __restrict__ b16)
{
    const int wv = threadIdx.x >> 6, lane = threadIdx.x & 63;
    const int sub = lane >> 4, ln = lane & 15;
    const int x0 = (blockIdx.x & 1) * 64, h = blockIdx.x >> 1;
    const int br = blockIdx.y % 3, b = blockIdx.y / 3;
    const int cnt = (br == 1) ? 12 : 3;
    const int mapb = (br == 0) ? 0 : (br == 1) ? 3 : 15;
    const int grpb = (br == 0) ? 0 : (br == 1) ? 9 : 19;
    const float* bias = (br == 0) ? chb : (br == 1) ? ohb : fhb;
    __shared__ __align__(16) ushortT sbuf[8 * 3 * 66 * 8];  // 25,344 B
    const int wbase = threadIdx.x & ~63;

    for (int it = 0; it < 7; ++it) {
        int idx = threadIdx.x + it * 256;
        if (idx < 1584) {
            int col = idx % 66, t2 = idx / 66;
            int r = t2 % 3, g = t2 / 3;
            const ushortT* gp = b16c +
                (((size_t)(b * 28 + grpb + g) * 134 + (h + r + 2)) * 134 + (x0 + col + 2)) * 8;
            gload_lds16(gp, sbuf + (size_t)(it * 256 + wbase) * 8);
        }
    }
    __syncthreads();

    floatx4 acc;
    #pragma unroll
    for (int r = 0; r < 4; ++r) acc[r] = 0.f;
    #pragma unroll
    for (int k = 0; k < 18; ++k) {
        int u = k * 4 + sub;
        int t = u >> 3, g = u & 7;
        int dxv = t % 3 - 1, ry = t / 3;
        short8 Af = *(const short8*)(wH + ((size_t)(br * 72 + u) * 16 + ln) * 8);
        int c = wv * 16 + ln + dxv + 1;
        short8 Bf = *(const short8*)(sbuf + ((g * 3 + ry) * 66 + c) * 8);
        acc = __builtin_amdgcn_mfma_f32_16x16x32_bf16(Af, Bf, acc, 0, 0, 0);
    }
    {
        int px = x0 + wv * 16 + ln;
        #pragma unroll
        for (int r = 0; r < 4; ++r) {
            int m = sub * 4 + r;
            if (m < cnt) {
                float v = acc[r] + bias[m];
                out[((size_t)b * 26 + mapb + m) * HW + h * WIMG + px] = v;
                int grp = grpb + 8 + (m >> 3), j = m & 7;
                b16[(((size_t)(b * 28 + grp) * 134 + (h + 3)) * 134 + (px + 3)) * 8 + j]
                    = f2bf(v);
            }
        }
    }
}

// ------ kv: full-row N=128, double-buffered, A-preload + late stage ---------
template<int BRV>
__device__ __forceinline__ void kv_body(
    const ushortT* __restrict__ b16, const ushortT* __restrict__ kvw,
    const float* __restrict__ geob, ushortT* __restrict__ kvout,
    ushortT* __restrict__ sbufRaw, int h, int b)
{
    constexpr int NG   = (BRV == 0) ? 9 : (BRV == 1) ? 10 : 9;   // channel groups
    constexpr int NTAP = (BRV == 0) ? 9 : (BRV == 1) ? 16 : 25;
    constexpr int NQ   = (BRV == 0) ? 3 : (BRV == 1) ? 4 : 7;    // tap quads (padded)
    constexpr int ROWS = (BRV == 0) ? 3 : (BRV == 1) ? 6 : 5;
    constexpr int COLS = (BRV == 0) ? 130 : (BRV == 1) ? 134 : 132;  // 128 + x-apron
    constexpr int XMIN = (BRV == 0) ? -1 : (BRV == 1) ? -3 : -2;
    constexpr int UBASE = (BRV == 0) ? 0 : (BRV == 1) ? 9 : 19;
    constexpr int NEL  = ROWS * COLS;            // 390 / 804 / 660 per group
    constexpr int NIT  = (NEL + 255) / 256;
    constexpr int WBASE = (BRV == 0) ? 0 : (BRV == 1) ? 110592 : 274432;  // ushorts

    const int lane = threadIdx.x & 63, wv = threadIdx.x >> 6;
    const int sub = lane >> 4, ln = lane & 15;
    const int wbase = threadIdx.x & ~63;
    const int thrB = ln * 16;

    // per-quad B byte offsets within the full-row group tile
    int boff[NQ];
    #pragma unroll
    for (int q = 0; q < NQ; ++q) {
        int t = q * 4 + sub;
        int dxv, ry;
        if (t >= NTAP)          { dxv = -XMIN; ry = 0; }  // padded tap: zero wt, safe addr
        else if (BRV == 0)      { dxv = t % 3 - 1; ry = t / 3; }
        else if (BRV == 1)      { dxv = tapX_cor[t]; ry = tapR_cor[t]; }
        else                    { dxv = t % 5 - 2; ry = t / 5; }
        boff[q] = (ry * COLS + (dxv - XMIN)) * 16 + thrB;
    }

    auto stage = [&](int g, int buf) {
        #pragma unroll
        for (int it = 0; it < NIT; ++it) {
            int idx = threadIdx.x + it * 256;
            if (idx < NEL) {
                int rw = idx / COLS, col = idx % COLS;
                int dy = (BRV == 1) ? ((rw < 3) ? rw - 3 : rw - 2) : (rw - ROWS / 2);
                const ushortT* gp = b16 +
                    (((size_t)(b * 28 + UBASE + g) * 134 + (h + dy + 3)) * 134
                     + (col + XMIN + 3)) * 8;
                gload_lds16(gp, sbufRaw + (size_t)buf * (NEL * 8)
                                        + (size_t)(it * 256 + wbase) * 8);
            }
        }
    };

    floatx4 acc[2][8];
    #pragma unroll
    for (int mt = 0; mt < 2; ++mt)
        #pragma unroll
        for (int nt = 0; nt < 8; ++nt)
            #pragma unroll
            for (int r = 0; r < 4; ++r) acc[mt][nt][r] = 0.f;

    const ushortT* wp0 = kvw + WBASE + (size_t)sub * 1024 + (wv * 32 + ln) * 8;

    stage(0, 0);
    int cur = 0;
    for (int g = 0; g < NG; ++g) {
        // drains stage(g) (vmcnt0 in barrier) and separates phase g-1 reads
        // from the stage(g+1) issue below (so dbuf WAR is safe).
        __syncthreads();
        const char* sb8 = (const char*)(sbufRaw + (size_t)cur * (NEL * 8));
        const ushortT* wg = wp0 + (size_t)g * (NQ * 4096);

        // preload ALL A fragments for this group (registers, static-indexed)
        short8 Areg[NQ][2];
        #pragma unroll
        for (int q = 0; q < NQ; ++q) {
            Areg[q][0] = *(const short8*)(wg + (size_t)q * 4096);
            Areg[q][1] = *(const short8*)(wg + (size_t)q * 4096 + 128);
        }
        // now (and only now) issue next-group stage: A-waits above precede it
        // in issue order, so waiting on A never drains the stage.
        if (g + 1 < NG) {
            __builtin_amdgcn_sched_barrier(0);
            stage(g + 1, cur ^ 1);
            __builtin_amdgcn_sched_barrier(0);
        }
        #pragma unroll
        for (int q = 0; q < NQ; ++q) {
            int bb = boff[q];
            #pragma unroll
            for (int nt = 0; nt < 8; ++nt) {
                short8 Bf = *(const short8*)(sb8 + bb + nt * 256);
                acc[0][nt] = __builtin_amdgcn_mfma_f32_16x16x32_bf16(
                    Areg[q][0], Bf, acc[0][nt], 0, 0, 0);
                acc[1][nt] = __builtin_amdgcn_mfma_f32_16x16x32_bf16(
                    Areg[q][1], Bf, acc[1][nt], 0, 0, 0);
            }
        }
        cur ^= 1;
    }

    // epilogue: + GA*fx + GB*fy + GC, relu, channel-major bf16 (full 256B lines)
    const float* geo = geob + BRV * 384;
    const float fy = (h + 0.5f) * 0.0078125f;
    #pragma unroll
    for (int mt = 0; mt < 2; ++mt)
        #pragma unroll
        for (int nt = 0; nt < 8; ++nt) {
            int px = nt * 16 + ln;
            float fx = (px + 0.5f) * 0.0078125f;
            #pragma unroll
            for (int r = 0; r < 4; ++r) {
                int Mi = wv * 32 + mt * 16 + sub * 4 + r;
                float v = acc[mt][nt][r] + geo[Mi] * fx + geo[128 + Mi] * fy + geo[256 + Mi];
                kvout[((size_t)(BRV * 4 + b) * 128 + Mi) * HW + h * WIMG + px] =
                    f2bf(fmaxf(v, 0.f));
            }
        }
}

__global__ __launch_bounds__(256, 3) void kv_all4(
    const ushortT* __restrict__ b16, const ushortT* __restrict__ kvw,
    const float* __restrict__ geob, ushortT* __restrict__ kvout)
{
    __shared__ __align__(16) ushortT sbuf[2 * 804 * 8];  // dbuf, union max (br1)
    const int h = blockIdx.x;
    const int z = blockIdx.y;            // brv*4 + b
    const int brv = z >> 2, b = z & 3;
    if (brv == 0)      kv_body<0>(b16, kvw, geob, kvout, sbuf, h, b);
    else if (brv == 1) kv_body<1>(b16, kvw, geob, kvout, sbuf, h, b);
    else               kv_body<2>(b16, kvw, geob, kvout, sbuf, h, b);
}

// -------- fused q-GEMM + attention softmax + p1(MFMA,K=320) + p2 ------------
__global__ __launch_bounds__(256) void attn_pred_mfma(
    float* __restrict__ ws, const float* __restrict__ p2w,
    const float* __restrict__ p2b, float* __restrict__ out)
{
    const int wv = threadIdx.x >> 6, lane = threadIdx.x & 63;
    const int sub = lane >> 4, ln = lane & 15;
    const int px0 = blockIdx.x * 64, b = blockIdx.y;
    const ushortT* wP1 = (const ushortT*)(ws + OFF_P1WT);
    const ushortT* wQ  = (const ushortT*)(ws + OFF_QWT);
    const ushortT* a16 = (const ushortT*)(ws + OFF_A16);
    const ushortT* kv = (const ushortT*)(ws + OFF_KV);
    const float* p1b = ws + OFF_P1B;
    const float* qb  = ws + OFF_QB;
    __shared__ __align__(16) ushortT xbuf[40 * 64 * 8];
    __shared__ __align__(16) ushortT qld[64 * 64];

    const int mypx = threadIdx.x & 63, nh = threadIdx.x >> 6;
    const int gpx = px0 + mypx, hh = gpx >> 7, ww = gpx & 127;
    #pragma unroll
    for (int g2 = 0; g2 < 8; ++g2) {
        int g = nh * 8 + g2;
        const ushortT* gp = a16 +
            (((size_t)(b * 32 + g) * 130 + (hh + 1)) * 130 + (ww + 1)) * 8;
        gload_lds16(gp, xbuf + (size_t)g * 64 * 8);
    }
    __syncthreads();

    {
        floatx4 qacc[4];
        #pragma unroll
        for (int nt = 0; nt < 4; ++nt)
            #pragma unroll
            for (int r = 0; r < 4; ++r) qacc[nt][r] = 0.f;
        #pragma unroll
        for (int kk = 0; kk < 8; ++kk) {
            short8 Af = *(const short8*)(wQ + (((kk * 4 + sub) * 64) + wv * 16 + ln) * 8);
            #pragma unroll
            for (int nt = 0; nt < 4; ++nt) {
                short8 Bf = *(const short8*)(xbuf + (((kk * 4 + sub) * 64) + nt * 16 + ln) * 8);
                qacc[nt] = __builtin_amdgcn_mfma_f32_16x16x32_bf16(Af, Bf, qacc[nt], 0, 0, 0);
            }
        }
        #pragma unroll
        for (int nt = 0; nt < 4; ++nt)
            #pragma unroll
            for (int r = 0; r < 4; ++r) {
                int row = wv * 16 + sub * 4 + r;
                qld[row * 64 + nt * 16 + ln] = f2bf(fmaxf(qacc[nt][r] + qb[row], 0.f));
            }
    }
    __syncthreads();

    {
        float l[3];
        #pragma unroll
        for (int br = 0; br < 3; ++br) {
            float s = 0.f;
            #pragma unroll
            for (int ko = 0; ko < 16; ++ko)
                s = fmaf(bf2f(qld[(nh * 16 + ko) * 64 + mypx]),
                         bf2f(kv[(size_t)((br * 4 + b) * 128 + nh * 16 + ko) * HW + gpx]), s);
            l[br] = s;
        }
        float m = fmaxf(l[0], fmaxf(l[1], l[2]));
        float e0 = __expf(l[0] - m), e1 = __expf(l[1] - m), e2 = __expf(l[2] - m);
        float inv = 1.f / (e0 + e1 + e2);
        float aw0 = e0 * inv, aw1 = e1 * inv, aw2 = e2 * inv;
        #pragma unroll
        for (int vap = 0; vap < 8; ++vap) {
            int va0 = vap * 2, va1 = vap * 2 + 1;
            float a0 =
                aw0 * bf2f(kv[(size_t)((0 * 4 + b) * 128 + 64 + nh * 16 + va0) * HW + gpx]) +
                aw1 * bf2f(kv[(size_t)((1 * 4 + b) * 128 + 64 + nh * 16 + va0) * HW + gpx]) +
                aw2 * bf2f(kv[(size_t)((2 * 4 + b) * 128 + 64 + nh * 16 + va0) * HW + gpx]);
            float a1 =
                aw0 * bf2f(kv[(size_t)((0 * 4 + b) * 128 + 64 + nh * 16 + va1) * HW + gpx]) +
                aw1 * bf2f(kv[(size_t)((1 * 4 + b) * 128 + 64 + nh * 16 + va1) * HW + gpx]) +
                aw2 * bf2f(kv[(size_t)((2 * 4 + b) * 128 + 64 + nh * 16 + va1) * HW + gpx]);
            int g = 32 + nh * 2 + (vap >> 2), wo = vap & 3;
            ((unsigned*)xbuf)[(g * 64 + mypx) * 4 + wo] = packbf(a0, a1);
        }
    }
    __syncthreads();

    floatx4 acc[4][4];
    #pragma unroll
    for (int mt = 0; mt < 4; ++mt)
        #pragma unroll
        for (int nt = 0; nt < 4; ++nt)
            #pragma unroll
            for (int r = 0; r < 4; ++r) acc[mt][nt][r] = 0.f;
    #pragma unroll
    for (int kk = 0; kk < 10; ++kk) {
        short8 Bf[4];
        #pragma unroll
        for (int nt = 0; nt < 4; ++nt)
            Bf[nt] = *(const short8*)(xbuf + (((kk * 4 + sub) * 64) + nt * 16 + ln) * 8);
        #pragma unroll
        for (int mt = 0; mt < 4; ++mt) {
            short8 Af = *(const short8*)(wP1 +
                (((size_t)(kk * 4 + sub) * 256) + wv * 64 + mt * 16 + ln) * 8);
            #pragma unroll
            for (int nt = 0; nt < 4; ++nt)
                acc[mt][nt] = __builtin_amdgcn_mfma_f32_16x16x32_bf16(Af, Bf[nt], acc[mt][nt], 0, 0, 0);
        }
    }

    float po0[4] = {0.f, 0.f, 0.f, 0.f}, po1[4] = {0.f, 0.f, 0.f, 0.f};
    #pragma unroll
    for (int mt = 0; mt < 4; ++mt)
        #pragma unroll
        for (int r = 0; r < 4; ++r) {
            int oc = mt * 16 + sub * 4 + r;
            float bias = p1b[wv * 64 + oc];
            float w0 = p2w[(wv * 2 + 0) * 64 + oc];
            float w1 = p2w[(wv * 2 + 1) * 64 + oc];
            #pragma unroll
            for (int nt = 0; nt < 4; ++nt) {
                float hv = fmaxf(acc[mt][nt][r] + bias, 0.f);
                po0[nt] = fmaf(w0, hv, po0[nt]);
                po1[nt] = fmaf(w1, hv, po1[nt]);
            }
        }
    #pragma unroll
    for (int nt = 0; nt < 4; ++nt) {
        po0[nt] += __shfl_xor(po0[nt], 16);
        po0[nt] += __shfl_xor(po0[nt], 32);
        po1[nt] += __shfl_xor(po1[nt], 16);
        po1[nt] += __shfl_xor(po1[nt], 32);
    }
    if (sub == 0) {
        #pragma unroll
        for (int nt = 0; nt < 4; ++nt) {
            int px = px0 + nt * 16 + ln;
            out[((size_t)b * 26 + 18 + wv * 2 + 0) * HW + px] = po0[nt] + p2b[wv * 2 + 0];
            out[((size_t)b * 26 + 18 + wv * 2 + 1) * HW + px] = po1[nt] + p2b[wv * 2 + 1];
        }
    }
}

// ---------------------------------------------------------------------------
extern "C" void kernel_launch(void* const* d_in, const int* in_sizes, int n_in,
                              void* d_out, int out_size, void* d_ws, size_t ws_size,
                              hipStream_t stream) {
    (void)in_sizes; (void)n_in; (void)out_size; (void)ws_size;
    float* ws  = (float*)d_ws;
    float* out = (float*)d_out;
    const float* base = (const float*)d_in[0];
    P53 ptrs;
    for (int i = 0; i < 53; ++i) ptrs.p[i] = (const float*)d_in[i];

    ushortT* a16 = (ushortT*)(ws + OFF_A16);
    ushortT* b16 = (ushortT*)(ws + OFF_B16);
    ushortT* kvb = (ushortT*)(ws + OFF_KV);
    const ushortT* kvw = (const ushortT*)(ws + OFF_KVW);

    setup_kernel<<<20613, 256, 0, stream>>>(ptrs, ws, base, a16, b16);
    conv_base_mfma<<<dim3(128, 4), 512, 0, stream>>>(
        a16, (const ushortT*)(ws + OFF_CWT), ws + OFF_CB, b16);
    conv_head_mfma<<<dim3(256, 12), 256, 0, stream>>>(
        b16, (const ushortT*)(ws + OFF_HWT),
        (const float*)d_in[6], (const float*)d_in[12], (const float*)d_in[18],
        out, b16);
    kv_all4<<<dim3(128, 12), 256, 0, stream>>>(b16, kvw, ws + OFF_GEO, kvb);
    attn_pred_mfma<<<dim3(256, 4), 256, 0, stream>>>(ws, (const float*)d_in[51],
                                                     (const float*)d_in[52], out);
}